// Round 1
// baseline (1623.181 us; speedup 1.0000x reference)
//
#include <hip/hip_runtime.h>
#include <math.h>

#define N_NODES 100000
#define N_EDGES 400000
#define N_GRAPHS_C 4096
#define E_TOT (N_EDGES + N_NODES)

static inline int ceil_div(int a, int b) { return (a + b - 1) / b; }

// ---------------- CSR build ----------------

__global__ __launch_bounds__(256) void k_count_deg(const int* __restrict__ ei, int* __restrict__ deg) {
  int i = blockIdx.x * 256 + threadIdx.x;
  if (i < N_EDGES) {
    int d = ei[N_EDGES + i];  // dst row
    atomicAdd(&deg[d], 1);
  }
}

// Exclusive-scan of (deg+1) with atomic block base (partition order arbitrary but consistent).
__global__ __launch_bounds__(256) void k_scan(int* __restrict__ deg, int* __restrict__ offs,
                                              int* __restrict__ cursor, int* __restrict__ counter) {
  __shared__ int sm[256];
  __shared__ int sbase;
  int tid = threadIdx.x;
  int n = blockIdx.x * 256 + tid;
  int d = (n < N_NODES) ? (deg[n] + 1) : 0;  // +1 self loop
  sm[tid] = d;
  __syncthreads();
  for (int off = 1; off < 256; off <<= 1) {
    int v = (tid >= off) ? sm[tid - off] : 0;
    __syncthreads();
    sm[tid] += v;
    __syncthreads();
  }
  if (tid == 255) sbase = atomicAdd(counter, sm[255]);
  __syncthreads();
  int excl = sm[tid] - d;
  if (n < N_NODES) {
    int o = sbase + excl;
    offs[n] = o;
    cursor[n] = o;
    deg[n] = d;  // now includes self loop
  }
}

__global__ __launch_bounds__(256) void k_scatter(const int* __restrict__ ei, int* __restrict__ cursor,
                                                 int* __restrict__ csr) {
  int i = blockIdx.x * 256 + threadIdx.x;
  if (i < N_EDGES) {
    int s = ei[i];
    int d = ei[N_EDGES + i];
    int pos = atomicAdd(&cursor[d], 1);
    csr[pos] = s;
  } else if (i < E_TOT) {
    int n = i - N_EDGES;
    int pos = atomicAdd(&cursor[n], 1);
    csr[pos] = n;  // self loop
  }
}

// ---------------- fp32 GEMM: out[M,Ncol] = A[M,K] @ W[K,Ncol] ----------------
// 64x64 tile, BK=16, 256 threads, 4x4 accum per thread.

__global__ __launch_bounds__(256) void k_gemm(const float* __restrict__ A, const float* __restrict__ W,
                                              float* __restrict__ out, int M, int K, int Ncol) {
  __shared__ float As[16][64];
  __shared__ float Ws[16][64];
  int tid = threadIdx.x;
  int tx = tid & 15, ty = tid >> 4;
  int row0 = blockIdx.x * 64, col0 = blockIdx.y * 64;
  float acc[4][4] = {};
  int arow = tid >> 2;        // 0..63
  int akq = (tid & 3) * 4;    // 0,4,8,12
  int wk = tid >> 4;          // 0..15
  int wc = (tid & 15) * 4;    // 0..60
  for (int k0 = 0; k0 < K; k0 += 16) {
    int gr = row0 + arow;
    float4 av = make_float4(0.f, 0.f, 0.f, 0.f);
    if (gr < M) av = *(const float4*)(A + (size_t)gr * K + k0 + akq);
    As[akq + 0][arow] = av.x;
    As[akq + 1][arow] = av.y;
    As[akq + 2][arow] = av.z;
    As[akq + 3][arow] = av.w;
    float4 wv = *(const float4*)(W + (size_t)(k0 + wk) * Ncol + col0 + wc);
    *(float4*)&Ws[wk][wc] = wv;
    __syncthreads();
#pragma unroll
    for (int k = 0; k < 16; k++) {
      float4 a = *(float4*)&As[k][ty * 4];
      float4 b = *(float4*)&Ws[k][tx * 4];
      acc[0][0] += a.x * b.x; acc[0][1] += a.x * b.y; acc[0][2] += a.x * b.z; acc[0][3] += a.x * b.w;
      acc[1][0] += a.y * b.x; acc[1][1] += a.y * b.y; acc[1][2] += a.y * b.z; acc[1][3] += a.y * b.w;
      acc[2][0] += a.z * b.x; acc[2][1] += a.z * b.y; acc[2][2] += a.z * b.z; acc[2][3] += a.z * b.w;
      acc[3][0] += a.w * b.x; acc[3][1] += a.w * b.y; acc[3][2] += a.w * b.z; acc[3][3] += a.w * b.w;
    }
    __syncthreads();
  }
#pragma unroll
  for (int r = 0; r < 4; r++) {
    int gr = row0 + ty * 4 + r;
    if (gr < M) {
      float4 v = make_float4(acc[r][0], acc[r][1], acc[r][2], acc[r][3]);
      *(float4*)(out + (size_t)gr * Ncol + col0 + tx * 4) = v;
    }
  }
}

// ---------------- attention logits ----------------
// es[n,h] = dot(h[n,h,:], a_s[h,:]); ed likewise. One thread per (n,h).

template <int H, int C>
__global__ __launch_bounds__(256) void k_att(const float* __restrict__ hbuf, const float* __restrict__ a_s,
                                             const float* __restrict__ a_d, float* __restrict__ es,
                                             float* __restrict__ ed) {
  int idx = blockIdx.x * 256 + threadIdx.x;
  if (idx >= N_NODES * H) return;
  int n = idx / H;
  int h = idx % H;
  const float* row = hbuf + (size_t)n * (H * C) + h * C;
  float s = 0.f, d = 0.f;
#pragma unroll 4
  for (int c = 0; c < C; c++) {
    float v = row[c];
    s += v * a_s[h * C + c];
    d += v * a_d[h * C + c];
  }
  es[idx] = s;
  ed[idx] = d;
}

// ---------------- softmax + aggregation ----------------
// One wave (64 lanes) per destination node; 3 passes over CSR edges.

template <int H, int C>
__global__ __launch_bounds__(256) void k_aggregate(const float* __restrict__ hbuf, const float* __restrict__ es,
                                                   const float* __restrict__ ed, const int* __restrict__ offs,
                                                   const int* __restrict__ deg, const int* __restrict__ csr,
                                                   const float* __restrict__ bias, float* __restrict__ out,
                                                   int applyElu) {
  constexpr int F = H * C;
  constexpr int VPL = F / 64;  // floats per lane: 4 (H=4,C=64) or 2 (H=1,C=128)
  int wave = threadIdx.x >> 6;
  int lane = threadIdx.x & 63;
  int n = blockIdx.x * 4 + wave;
  if (n >= N_NODES) return;
  int head = (H == 1) ? 0 : (lane >> 4);
  int start = offs[n];
  int cnt = deg[n];
  float edn = ed[n * H + head];

  float m = -1e30f;
  for (int i = 0; i < cnt; i++) {
    int s = csr[start + i];
    float e = es[s * H + head] + edn;
    e = e > 0.f ? e : 0.2f * e;
    m = fmaxf(m, e);
  }
  float denom = 0.f;
  for (int i = 0; i < cnt; i++) {
    int s = csr[start + i];
    float e = es[s * H + head] + edn;
    e = e > 0.f ? e : 0.2f * e;
    denom += __expf(e - m);
  }
  float inv = 1.0f / fmaxf(denom, 1e-16f);

  float acc[VPL];
#pragma unroll
  for (int j = 0; j < VPL; j++) acc[j] = 0.f;

  for (int i = 0; i < cnt; i++) {
    int s = csr[start + i];
    float e = es[s * H + head] + edn;
    e = e > 0.f ? e : 0.2f * e;
    float w = __expf(e - m) * inv;
    const float* hp = hbuf + (size_t)s * F + lane * VPL;
    if (VPL == 4) {
      float4 v = *(const float4*)hp;
      acc[0] += w * v.x; acc[1] += w * v.y; acc[2] += w * v.z; acc[3] += w * v.w;
    } else {
      float2 v = *(const float2*)hp;
      acc[0] += w * v.x; acc[1] += w * v.y;
    }
  }

#pragma unroll
  for (int j = 0; j < VPL; j++) {
    float v = acc[j] + bias[lane * VPL + j];
    if (applyElu) v = v > 0.f ? v : expm1f(v);
    out[(size_t)n * F + lane * VPL + j] = v;
  }
}

// ---------------- per-graph mean pool (atomic sums) ----------------

__global__ __launch_bounds__(256) void k_pool(const float* __restrict__ feat, const int* __restrict__ batch,
                                              float* __restrict__ pool, float* __restrict__ cnt) {
  int wave = threadIdx.x >> 6;
  int lane = threadIdx.x & 63;
  int n = blockIdx.x * 4 + wave;
  if (n >= N_NODES) return;
  int g = batch[n];
  const float* row = feat + (size_t)n * 128;
  float2 v = *(const float2*)(row + lane * 2);
  atomicAdd(&pool[g * 128 + lane * 2 + 0], v.x);
  atomicAdd(&pool[g * 128 + lane * 2 + 1], v.y);
  if (lane == 0) atomicAdd(&cnt[g], 1.0f);
}

// ---------------- MLP readout: 128 -> 64 -> 32 -> 4 ----------------

__global__ __launch_bounds__(128) void k_readout(const float* __restrict__ pool, const float* __restrict__ cnt,
                                                 const float* __restrict__ mW0, const float* __restrict__ mb0,
                                                 const float* __restrict__ mW1, const float* __restrict__ mb1,
                                                 const float* __restrict__ mW2, const float* __restrict__ mb2,
                                                 float* __restrict__ out) {
  __shared__ float p[128];
  __shared__ float y1[64];
  __shared__ float y2[32];
  int g = blockIdx.x;
  int t = threadIdx.x;
  float c = cnt[g];
  float invc = 1.0f / fmaxf(c, 1.0f);
  p[t] = pool[(size_t)g * 128 + t] * invc;
  __syncthreads();
  if (t < 64) {
    float a = mb0[t];
#pragma unroll 4
    for (int k = 0; k < 128; k++) a += p[k] * mW0[k * 64 + t];
    y1[t] = a > 0.f ? a : 0.f;
  }
  __syncthreads();
  if (t < 32) {
    float a = mb1[t];
#pragma unroll 4
    for (int k = 0; k < 64; k++) a += y1[k] * mW1[k * 32 + t];
    y2[t] = a > 0.f ? a : 0.f;
  }
  __syncthreads();
  if (t < 4) {
    float a = mb2[t];
#pragma unroll 4
    for (int k = 0; k < 32; k++) a += y2[k] * mW2[k * 4 + t];
    out[(size_t)g * 4 + t] = a;
  }
}

// ---------------- host side ----------------

extern "C" void kernel_launch(void* const* d_in, const int* in_sizes, int n_in,
                              void* d_out, int out_size, void* d_ws, size_t ws_size,
                              hipStream_t stream) {
  const float* x = (const float*)d_in[0];
  const int* ei = (const int*)d_in[1];
  const int* batch = (const int*)d_in[2];
  // d_in[3] = num_graphs (unused, constant 4096)
  const float* W0 = (const float*)d_in[4];
  const float* as0 = (const float*)d_in[5];
  const float* ad0 = (const float*)d_in[6];
  const float* b0 = (const float*)d_in[7];
  const float* W1 = (const float*)d_in[8];
  const float* as1 = (const float*)d_in[9];
  const float* ad1 = (const float*)d_in[10];
  const float* b1 = (const float*)d_in[11];
  const float* W2 = (const float*)d_in[12];
  const float* as2 = (const float*)d_in[13];
  const float* ad2 = (const float*)d_in[14];
  const float* b2 = (const float*)d_in[15];
  const float* W3 = (const float*)d_in[16];
  const float* as3 = (const float*)d_in[17];
  const float* ad3 = (const float*)d_in[18];
  const float* b3 = (const float*)d_in[19];
  const float* mW0 = (const float*)d_in[20];
  const float* mb0 = (const float*)d_in[21];
  const float* mW1 = (const float*)d_in[22];
  const float* mb1 = (const float*)d_in[23];
  const float* mW2 = (const float*)d_in[24];
  const float* mb2 = (const float*)d_in[25];
  float* out = (float*)d_out;

  // workspace bump allocator
  char* ws = (char*)d_ws;
  size_t cur = 0;
  auto alloc = [&](size_t bytes) -> char* {
    char* p = ws + cur;
    cur += (bytes + 255) & ~(size_t)255;
    return p;
  };
  const size_t featBytes = (size_t)N_NODES * 256 * sizeof(float);
  float* featA = (float*)alloc(featBytes);  // layer input/output features
  float* hB = (float*)alloc(featBytes);     // GEMM output h
  float* es = (float*)alloc((size_t)N_NODES * 4 * sizeof(float));
  float* ed = (float*)alloc((size_t)N_NODES * 4 * sizeof(float));
  int* deg = (int*)alloc((size_t)N_NODES * sizeof(int));
  int* offs = (int*)alloc((size_t)N_NODES * sizeof(int));
  int* cursor = (int*)alloc((size_t)N_NODES * sizeof(int));
  int* csr = (int*)alloc((size_t)E_TOT * sizeof(int));
  float* pool = (float*)alloc((size_t)N_GRAPHS_C * 128 * sizeof(float));
  float* cnt = (float*)alloc((size_t)N_GRAPHS_C * sizeof(float));
  int* counter = (int*)alloc(256);
  (void)ws_size; (void)in_sizes; (void)n_in; (void)out_size;

  // ---- CSR build ----
  hipMemsetAsync(deg, 0, (size_t)N_NODES * sizeof(int), stream);
  hipMemsetAsync(counter, 0, sizeof(int), stream);
  k_count_deg<<<ceil_div(N_EDGES, 256), 256, 0, stream>>>(ei, deg);
  k_scan<<<ceil_div(N_NODES, 256), 256, 0, stream>>>(deg, offs, cursor, counter);
  k_scatter<<<ceil_div(E_TOT, 256), 256, 0, stream>>>(ei, cursor, csr);

  int gx = ceil_div(N_NODES, 64);
  dim3 g256(gx, 4), g128(gx, 2);
  int aggBlocks = ceil_div(N_NODES, 4);

  // ---- layer 0: 64 -> 4x64 ----
  k_gemm<<<g256, 256, 0, stream>>>(x, W0, hB, N_NODES, 64, 256);
  k_att<4, 64><<<ceil_div(N_NODES * 4, 256), 256, 0, stream>>>(hB, as0, ad0, es, ed);
  k_aggregate<4, 64><<<aggBlocks, 256, 0, stream>>>(hB, es, ed, offs, deg, csr, b0, featA, 1);

  // ---- layer 1 ----
  k_gemm<<<g256, 256, 0, stream>>>(featA, W1, hB, N_NODES, 256, 256);
  k_att<4, 64><<<ceil_div(N_NODES * 4, 256), 256, 0, stream>>>(hB, as1, ad1, es, ed);
  k_aggregate<4, 64><<<aggBlocks, 256, 0, stream>>>(hB, es, ed, offs, deg, csr, b1, featA, 1);

  // ---- layer 2 ----
  k_gemm<<<g256, 256, 0, stream>>>(featA, W2, hB, N_NODES, 256, 256);
  k_att<4, 64><<<ceil_div(N_NODES * 4, 256), 256, 0, stream>>>(hB, as2, ad2, es, ed);
  k_aggregate<4, 64><<<aggBlocks, 256, 0, stream>>>(hB, es, ed, offs, deg, csr, b2, featA, 1);

  // ---- layer 3: 256 -> 128 (1 head, mean == identity, no ELU) ----
  k_gemm<<<g128, 256, 0, stream>>>(featA, W3, hB, N_NODES, 256, 128);
  k_att<1, 128><<<ceil_div(N_NODES, 256), 256, 0, stream>>>(hB, as3, ad3, es, ed);
  k_aggregate<1, 128><<<aggBlocks, 256, 0, stream>>>(hB, es, ed, offs, deg, csr, b3, featA, 0);

  // ---- pool + readout ----
  hipMemsetAsync(pool, 0, (size_t)N_GRAPHS_C * 128 * sizeof(float), stream);
  hipMemsetAsync(cnt, 0, (size_t)N_GRAPHS_C * sizeof(float), stream);
  k_pool<<<aggBlocks, 256, 0, stream>>>(featA, batch, pool, cnt);
  k_readout<<<N_GRAPHS_C, 128, 0, stream>>>(pool, cnt, mW0, mb0, mW1, mb1, mW2, mb2, out);
}

// Round 2
// 948.431 us; speedup vs baseline: 1.7114x; 1.7114x over previous
//
#include <hip/hip_runtime.h>
#include <math.h>

#define N_NODES 100000
#define N_EDGES 400000
#define N_GRAPHS_C 4096
#define E_TOT (N_EDGES + N_NODES)

static inline int ceil_div(int a, int b) { return (a + b - 1) / b; }

typedef __attribute__((ext_vector_type(8))) short short8v;
typedef __attribute__((ext_vector_type(4))) float float4v;

__device__ __forceinline__ float b2f(unsigned short u) {
  union { unsigned int i; float f; } v;
  v.i = ((unsigned int)u) << 16;
  return v.f;
}
__device__ __forceinline__ unsigned short f2b(float f) {
  union { float f; unsigned int i; } v;
  v.f = f;
  unsigned int x = v.i;
  unsigned int r = x + 0x7fffu + ((x >> 16) & 1u);  // RNE
  return (unsigned short)(r >> 16);
}

// ---------------- dtype conversion ----------------

__global__ __launch_bounds__(256) void k_cvt_x(const float* __restrict__ in, unsigned short* __restrict__ out,
                                               int n4) {
  int i = blockIdx.x * 256 + threadIdx.x;
  if (i >= n4) return;
  float4 v = *(const float4*)(in + (size_t)i * 4);
  ushort4 o;
  o.x = f2b(v.x); o.y = f2b(v.y); o.z = f2b(v.z); o.w = f2b(v.w);
  *(ushort4*)(out + (size_t)i * 4) = o;
}

// W[K,N] fp32 -> Wt[N,K] bf16
__global__ __launch_bounds__(256) void k_cvt_wt(const float* __restrict__ W, unsigned short* __restrict__ Wt,
                                                int K, int Ncol) {
  int i = blockIdx.x * 256 + threadIdx.x;
  if (i >= K * Ncol) return;
  int n = i / K, k = i % K;
  Wt[(size_t)n * K + k] = f2b(W[(size_t)k * Ncol + n]);
}

// ---------------- CSR build ----------------

__global__ __launch_bounds__(256) void k_count_deg(const int* __restrict__ ei, int* __restrict__ deg) {
  int i = blockIdx.x * 256 + threadIdx.x;
  if (i < N_EDGES) atomicAdd(&deg[ei[N_EDGES + i]], 1);
}

__global__ __launch_bounds__(256) void k_scan(int* __restrict__ deg, int* __restrict__ offs,
                                              int* __restrict__ cursor, int* __restrict__ counter) {
  __shared__ int sm[256];
  __shared__ int sbase;
  int tid = threadIdx.x;
  int n = blockIdx.x * 256 + tid;
  int d = (n < N_NODES) ? (deg[n] + 1) : 0;  // +1 self loop
  sm[tid] = d;
  __syncthreads();
  for (int off = 1; off < 256; off <<= 1) {
    int v = (tid >= off) ? sm[tid - off] : 0;
    __syncthreads();
    sm[tid] += v;
    __syncthreads();
  }
  if (tid == 255) sbase = atomicAdd(counter, sm[255]);
  __syncthreads();
  int excl = sm[tid] - d;
  if (n < N_NODES) {
    int o = sbase + excl;
    offs[n] = o;
    cursor[n] = o;
    deg[n] = d;
  }
}

__global__ __launch_bounds__(256) void k_scatter(const int* __restrict__ ei, int* __restrict__ cursor,
                                                 int* __restrict__ csr) {
  int i = blockIdx.x * 256 + threadIdx.x;
  if (i < N_EDGES) {
    int pos = atomicAdd(&cursor[ei[N_EDGES + i]], 1);
    csr[pos] = ei[i];
  } else if (i < E_TOT) {
    int n = i - N_EDGES;
    int pos = atomicAdd(&cursor[n], 1);
    csr[pos] = n;  // self loop
  }
}

// ---------------- bf16 MFMA GEMM: out[M,N] = A[M,K] @ Wt[N,K]^T ----------------
// 128x128 tile, BK=32, 256 threads = 4 waves in 2x2, each wave 64x64 via 4x4 MFMA 16x16x32.
// LDS rows padded to 40 bf16 (80B): fragment ds_read_b128 is 2-way-bank (free).

#define LDA 40

__global__ __launch_bounds__(256) void k_gemm_bf16(const unsigned short* __restrict__ A,
                                                   const unsigned short* __restrict__ Wt,
                                                   unsigned short* __restrict__ out, int M, int K, int Ncol) {
  __shared__ unsigned short As[128 * LDA];
  __shared__ unsigned short Bs[128 * LDA];
  int tid = threadIdx.x;
  int wave = tid >> 6, lane = tid & 63;
  int quad = lane >> 4, l16 = lane & 15;
  int wrow = (wave & 1) * 64, wcol = (wave >> 1) * 64;
  int row0 = blockIdx.x * 128, col0 = blockIdx.y * 128;

  float4v acc[4][4];
#pragma unroll
  for (int i = 0; i < 4; i++)
#pragma unroll
    for (int j = 0; j < 4; j++) acc[i][j] = (float4v)(0.f);

  // staging map: chunk q in [0,512): row=q>>2, 16B chunk c=q&3
  int r0 = tid >> 2, c0 = (tid & 3) * 8;
  int r1 = (tid + 256) >> 2, c1 = c0;

  for (int k0 = 0; k0 < K; k0 += 32) {
    uint4 a0 = make_uint4(0, 0, 0, 0), a1 = make_uint4(0, 0, 0, 0);
    if (row0 + r0 < M) a0 = *(const uint4*)(A + (size_t)(row0 + r0) * K + k0 + c0);
    if (row0 + r1 < M) a1 = *(const uint4*)(A + (size_t)(row0 + r1) * K + k0 + c1);
    uint4 b0 = *(const uint4*)(Wt + (size_t)(col0 + r0) * K + k0 + c0);
    uint4 b1 = *(const uint4*)(Wt + (size_t)(col0 + r1) * K + k0 + c1);
    __syncthreads();
    *(uint4*)(&As[r0 * LDA + c0]) = a0;
    *(uint4*)(&As[r1 * LDA + c1]) = a1;
    *(uint4*)(&Bs[r0 * LDA + c0]) = b0;
    *(uint4*)(&Bs[r1 * LDA + c1]) = b1;
    __syncthreads();

    short8v af[4], bf[4];
#pragma unroll
    for (int i = 0; i < 4; i++)
      af[i] = *(const short8v*)(&As[(wrow + i * 16 + l16) * LDA + quad * 8]);
#pragma unroll
    for (int j = 0; j < 4; j++)
      bf[j] = *(const short8v*)(&Bs[(wcol + j * 16 + l16) * LDA + quad * 8]);
#pragma unroll
    for (int i = 0; i < 4; i++)
#pragma unroll
      for (int j = 0; j < 4; j++)
        acc[i][j] = __builtin_amdgcn_mfma_f32_16x16x32_bf16(af[i], bf[j], acc[i][j], 0, 0, 0);
  }

#pragma unroll
  for (int i = 0; i < 4; i++) {
#pragma unroll
    for (int r = 0; r < 4; r++) {
      int m = row0 + wrow + i * 16 + quad * 4 + r;
      if (m < M) {
#pragma unroll
        for (int j = 0; j < 4; j++) {
          int col = col0 + wcol + j * 16 + l16;
          out[(size_t)m * Ncol + col] = f2b(acc[i][j][r]);
        }
      }
    }
  }
}

// ---------------- attention logits (bf16 h, fp32 a) ----------------

template <int H, int C>
__global__ __launch_bounds__(256) void k_att(const unsigned short* __restrict__ hbuf,
                                             const float* __restrict__ a_s, const float* __restrict__ a_d,
                                             float* __restrict__ es, float* __restrict__ ed) {
  int idx = blockIdx.x * 256 + threadIdx.x;
  if (idx >= N_NODES * H) return;
  int n = idx / H;
  int h = idx % H;
  const unsigned short* row = hbuf + (size_t)n * (H * C) + h * C;
  float s = 0.f, d = 0.f;
#pragma unroll 4
  for (int c = 0; c < C; c += 2) {
    unsigned int u = *(const unsigned int*)(row + c);
    float v0 = b2f((unsigned short)(u & 0xffff));
    float v1 = b2f((unsigned short)(u >> 16));
    s += v0 * a_s[h * C + c] + v1 * a_s[h * C + c + 1];
    d += v0 * a_d[h * C + c] + v1 * a_d[h * C + c + 1];
  }
  es[idx] = s;
  ed[idx] = d;
}

// ---------------- softmax + aggregation (2-pass, bf16 features) ----------------

template <int H, int C>
__global__ __launch_bounds__(256) void k_aggregate(const unsigned short* __restrict__ hbuf,
                                                   const float* __restrict__ es, const float* __restrict__ ed,
                                                   const int* __restrict__ offs, const int* __restrict__ deg,
                                                   const int* __restrict__ csr, const float* __restrict__ bias,
                                                   unsigned short* __restrict__ out, int applyElu) {
  constexpr int F = H * C;
  constexpr int VPL = F / 64;  // 4 (H=4,C=64) or 2 (H=1,C=128)
  int wave = threadIdx.x >> 6;
  int lane = threadIdx.x & 63;
  int n = blockIdx.x * 4 + wave;
  if (n >= N_NODES) return;
  int head = (H == 1) ? 0 : (lane >> 4);
  int start = offs[n];
  int cnt = deg[n];
  float edn = ed[n * H + head];

  float m = -1e30f;
  for (int i = 0; i < cnt; i++) {
    int s = csr[start + i];
    float e = es[s * H + head] + edn;
    e = e > 0.f ? e : 0.2f * e;
    m = fmaxf(m, e);
  }

  float denom = 0.f;
  float acc[VPL];
#pragma unroll
  for (int j = 0; j < VPL; j++) acc[j] = 0.f;

  for (int i = 0; i < cnt; i++) {
    int s = csr[start + i];
    float e = es[s * H + head] + edn;
    e = e > 0.f ? e : 0.2f * e;
    float w = __expf(e - m);
    denom += w;
    const unsigned short* hp = hbuf + (size_t)s * F + lane * VPL;
    if (VPL == 4) {
      uint2 u = *(const uint2*)hp;
      acc[0] += w * b2f((unsigned short)(u.x & 0xffff));
      acc[1] += w * b2f((unsigned short)(u.x >> 16));
      acc[2] += w * b2f((unsigned short)(u.y & 0xffff));
      acc[3] += w * b2f((unsigned short)(u.y >> 16));
    } else {
      unsigned int u = *(const unsigned int*)hp;
      acc[0] += w * b2f((unsigned short)(u & 0xffff));
      acc[1] += w * b2f((unsigned short)(u >> 16));
    }
  }
  float inv = 1.0f / fmaxf(denom, 1e-16f);

  unsigned short ob[VPL];
#pragma unroll
  for (int j = 0; j < VPL; j++) {
    float v = acc[j] * inv + bias[lane * VPL + j];
    if (applyElu) v = v > 0.f ? v : expm1f(v);
    ob[j] = f2b(v);
  }
  if (VPL == 4) {
    ushort4 o = make_ushort4(ob[0], ob[1], ob[2], ob[3]);
    *(ushort4*)(out + (size_t)n * F + lane * 4) = o;
  } else {
    ushort2 o = make_ushort2(ob[0], ob[1]);
    *(ushort2*)(out + (size_t)n * F + lane * 2) = o;
  }
}

// ---------------- per-graph mean pool ----------------

__global__ __launch_bounds__(256) void k_pool(const unsigned short* __restrict__ feat,
                                              const int* __restrict__ batch, float* __restrict__ pool,
                                              float* __restrict__ cnt) {
  int wave = threadIdx.x >> 6;
  int lane = threadIdx.x & 63;
  int n = blockIdx.x * 4 + wave;
  if (n >= N_NODES) return;
  int g = batch[n];
  unsigned int u = *(const unsigned int*)(feat + (size_t)n * 128 + lane * 2);
  atomicAdd(&pool[g * 128 + lane * 2 + 0], b2f((unsigned short)(u & 0xffff)));
  atomicAdd(&pool[g * 128 + lane * 2 + 1], b2f((unsigned short)(u >> 16)));
  if (lane == 0) atomicAdd(&cnt[g], 1.0f);
}

// ---------------- MLP readout: 128 -> 64 -> 32 -> 4 ----------------

__global__ __launch_bounds__(128) void k_readout(const float* __restrict__ pool, const float* __restrict__ cnt,
                                                 const float* __restrict__ mW0, const float* __restrict__ mb0,
                                                 const float* __restrict__ mW1, const float* __restrict__ mb1,
                                                 const float* __restrict__ mW2, const float* __restrict__ mb2,
                                                 float* __restrict__ out) {
  __shared__ float p[128];
  __shared__ float y1[64];
  __shared__ float y2[32];
  int g = blockIdx.x;
  int t = threadIdx.x;
  float invc = 1.0f / fmaxf(cnt[g], 1.0f);
  p[t] = pool[(size_t)g * 128 + t] * invc;
  __syncthreads();
  if (t < 64) {
    float a = mb0[t];
#pragma unroll 4
    for (int k = 0; k < 128; k++) a += p[k] * mW0[k * 64 + t];
    y1[t] = a > 0.f ? a : 0.f;
  }
  __syncthreads();
  if (t < 32) {
    float a = mb1[t];
#pragma unroll 4
    for (int k = 0; k < 64; k++) a += y1[k] * mW1[k * 32 + t];
    y2[t] = a > 0.f ? a : 0.f;
  }
  __syncthreads();
  if (t < 4) {
    float a = mb2[t];
#pragma unroll 4
    for (int k = 0; k < 32; k++) a += y2[k] * mW2[k * 4 + t];
    out[(size_t)g * 4 + t] = a;
  }
}

// ---------------- host side ----------------

extern "C" void kernel_launch(void* const* d_in, const int* in_sizes, int n_in,
                              void* d_out, int out_size, void* d_ws, size_t ws_size,
                              hipStream_t stream) {
  const float* x = (const float*)d_in[0];
  const int* ei = (const int*)d_in[1];
  const int* batch = (const int*)d_in[2];
  const float* W0 = (const float*)d_in[4];
  const float* as0 = (const float*)d_in[5];
  const float* ad0 = (const float*)d_in[6];
  const float* b0 = (const float*)d_in[7];
  const float* W1 = (const float*)d_in[8];
  const float* as1 = (const float*)d_in[9];
  const float* ad1 = (const float*)d_in[10];
  const float* b1 = (const float*)d_in[11];
  const float* W2 = (const float*)d_in[12];
  const float* as2 = (const float*)d_in[13];
  const float* ad2 = (const float*)d_in[14];
  const float* b2 = (const float*)d_in[15];
  const float* W3 = (const float*)d_in[16];
  const float* as3 = (const float*)d_in[17];
  const float* ad3 = (const float*)d_in[18];
  const float* b3 = (const float*)d_in[19];
  const float* mW0 = (const float*)d_in[20];
  const float* mb0 = (const float*)d_in[21];
  const float* mW1 = (const float*)d_in[22];
  const float* mb1 = (const float*)d_in[23];
  const float* mW2 = (const float*)d_in[24];
  const float* mb2 = (const float*)d_in[25];
  float* out = (float*)d_out;

  char* ws = (char*)d_ws;
  size_t cur = 0;
  auto alloc = [&](size_t bytes) -> char* {
    char* p = ws + cur;
    cur += (bytes + 255) & ~(size_t)255;
    return p;
  };
  unsigned short* featA = (unsigned short*)alloc((size_t)N_NODES * 256 * 2);
  unsigned short* hB = (unsigned short*)alloc((size_t)N_NODES * 256 * 2);
  unsigned short* xb = (unsigned short*)alloc((size_t)N_NODES * 64 * 2);
  unsigned short* wt0 = (unsigned short*)alloc((size_t)256 * 64 * 2);
  unsigned short* wt1 = (unsigned short*)alloc((size_t)256 * 256 * 2);
  unsigned short* wt2 = (unsigned short*)alloc((size_t)256 * 256 * 2);
  unsigned short* wt3 = (unsigned short*)alloc((size_t)128 * 256 * 2);
  float* es = (float*)alloc((size_t)N_NODES * 4 * sizeof(float));
  float* ed = (float*)alloc((size_t)N_NODES * 4 * sizeof(float));
  int* deg = (int*)alloc((size_t)N_NODES * sizeof(int));
  int* offs = (int*)alloc((size_t)N_NODES * sizeof(int));
  int* cursor = (int*)alloc((size_t)N_NODES * sizeof(int));
  int* csr = (int*)alloc((size_t)E_TOT * sizeof(int));
  float* pool = (float*)alloc((size_t)N_GRAPHS_C * 128 * sizeof(float));
  float* cnt = (float*)alloc((size_t)N_GRAPHS_C * sizeof(float));
  int* counter = (int*)alloc(256);
  (void)ws_size; (void)in_sizes; (void)n_in; (void)out_size;

  // ---- conversions ----
  k_cvt_x<<<ceil_div(N_NODES * 64 / 4, 256), 256, 0, stream>>>(x, xb, N_NODES * 64 / 4);
  k_cvt_wt<<<ceil_div(64 * 256, 256), 256, 0, stream>>>(W0, wt0, 64, 256);
  k_cvt_wt<<<ceil_div(256 * 256, 256), 256, 0, stream>>>(W1, wt1, 256, 256);
  k_cvt_wt<<<ceil_div(256 * 256, 256), 256, 0, stream>>>(W2, wt2, 256, 256);
  k_cvt_wt<<<ceil_div(256 * 128, 256), 256, 0, stream>>>(W3, wt3, 256, 128);

  // ---- CSR build ----
  hipMemsetAsync(deg, 0, (size_t)N_NODES * sizeof(int), stream);
  hipMemsetAsync(counter, 0, sizeof(int), stream);
  k_count_deg<<<ceil_div(N_EDGES, 256), 256, 0, stream>>>(ei, deg);
  k_scan<<<ceil_div(N_NODES, 256), 256, 0, stream>>>(deg, offs, cursor, counter);
  k_scatter<<<ceil_div(E_TOT, 256), 256, 0, stream>>>(ei, cursor, csr);

  int gm = ceil_div(N_NODES, 128);
  dim3 g256(gm, 2), g128(gm, 1);
  int aggBlocks = ceil_div(N_NODES, 4);

  // ---- layer 0: 64 -> 4x64 ----
  k_gemm_bf16<<<g256, 256, 0, stream>>>(xb, wt0, hB, N_NODES, 64, 256);
  k_att<4, 64><<<ceil_div(N_NODES * 4, 256), 256, 0, stream>>>(hB, as0, ad0, es, ed);
  k_aggregate<4, 64><<<aggBlocks, 256, 0, stream>>>(hB, es, ed, offs, deg, csr, b0, featA, 1);

  // ---- layer 1 ----
  k_gemm_bf16<<<g256, 256, 0, stream>>>(featA, wt1, hB, N_NODES, 256, 256);
  k_att<4, 64><<<ceil_div(N_NODES * 4, 256), 256, 0, stream>>>(hB, as1, ad1, es, ed);
  k_aggregate<4, 64><<<aggBlocks, 256, 0, stream>>>(hB, es, ed, offs, deg, csr, b1, featA, 1);

  // ---- layer 2 ----
  k_gemm_bf16<<<g256, 256, 0, stream>>>(featA, wt2, hB, N_NODES, 256, 256);
  k_att<4, 64><<<ceil_div(N_NODES * 4, 256), 256, 0, stream>>>(hB, as2, ad2, es, ed);
  k_aggregate<4, 64><<<aggBlocks, 256, 0, stream>>>(hB, es, ed, offs, deg, csr, b2, featA, 1);

  // ---- layer 3: 256 -> 128, 1 head, no ELU ----
  k_gemm_bf16<<<g128, 256, 0, stream>>>(featA, wt3, hB, N_NODES, 256, 128);
  k_att<1, 128><<<ceil_div(N_NODES, 256), 256, 0, stream>>>(hB, as3, ad3, es, ed);
  k_aggregate<1, 128><<<aggBlocks, 256, 0, stream>>>(hB, es, ed, offs, deg, csr, b3, featA, 0);

  // ---- pool + readout ----
  hipMemsetAsync(pool, 0, (size_t)N_GRAPHS_C * 128 * sizeof(float), stream);
  hipMemsetAsync(cnt, 0, (size_t)N_GRAPHS_C * sizeof(float), stream);
  k_pool<<<aggBlocks, 256, 0, stream>>>(featA, batch, pool, cnt);
  k_readout<<<N_GRAPHS_C, 128, 0, stream>>>(pool, cnt, mW0, mb0, mW1, mb1, mW2, mb2, out);
}

// Round 3
// 831.669 us; speedup vs baseline: 1.9517x; 1.1404x over previous
//
#include <hip/hip_runtime.h>
#include <math.h>

#define N_NODES 100000
#define N_EDGES 400000
#define N_GRAPHS_C 4096
#define E_TOT (N_EDGES + N_NODES)

static inline int ceil_div(int a, int b) { return (a + b - 1) / b; }

typedef __attribute__((ext_vector_type(8))) short short8v;
typedef __attribute__((ext_vector_type(4))) float float4v;

__device__ __forceinline__ float b2f(unsigned short u) {
  union { unsigned int i; float f; } v;
  v.i = ((unsigned int)u) << 16;
  return v.f;
}
__device__ __forceinline__ unsigned short f2b(float f) {
  union { float f; unsigned int i; } v;
  v.f = f;
  unsigned int x = v.i;
  unsigned int r = x + 0x7fffu + ((x >> 16) & 1u);  // RNE
  return (unsigned short)(r >> 16);
}

// ---------------- dtype conversion ----------------

__global__ __launch_bounds__(256) void k_cvt_x(const float* __restrict__ in, unsigned short* __restrict__ out,
                                               int n4) {
  int i = blockIdx.x * 256 + threadIdx.x;
  if (i >= n4) return;
  float4 v = *(const float4*)(in + (size_t)i * 4);
  ushort4 o;
  o.x = f2b(v.x); o.y = f2b(v.y); o.z = f2b(v.z); o.w = f2b(v.w);
  *(ushort4*)(out + (size_t)i * 4) = o;
}

// W[K,N] fp32 -> Wt[N,K] bf16
__global__ __launch_bounds__(256) void k_cvt_wt(const float* __restrict__ W, unsigned short* __restrict__ Wt,
                                                int K, int Ncol) {
  int i = blockIdx.x * 256 + threadIdx.x;
  if (i >= K * Ncol) return;
  int n = i / K, k = i % K;
  Wt[(size_t)n * K + k] = f2b(W[(size_t)k * Ncol + n]);
}

// ---------------- CSR build ----------------

__global__ __launch_bounds__(256) void k_count_deg(const int* __restrict__ ei, int* __restrict__ deg) {
  int i = blockIdx.x * 256 + threadIdx.x;
  if (i < N_EDGES) atomicAdd(&deg[ei[N_EDGES + i]], 1);
}

__global__ __launch_bounds__(256) void k_scan(int* __restrict__ deg, int* __restrict__ offs,
                                              int* __restrict__ cursor, int* __restrict__ counter) {
  __shared__ int sm[256];
  __shared__ int sbase;
  int tid = threadIdx.x;
  int n = blockIdx.x * 256 + tid;
  int d = (n < N_NODES) ? (deg[n] + 1) : 0;  // +1 self loop
  sm[tid] = d;
  __syncthreads();
  for (int off = 1; off < 256; off <<= 1) {
    int v = (tid >= off) ? sm[tid - off] : 0;
    __syncthreads();
    sm[tid] += v;
    __syncthreads();
  }
  if (tid == 255) sbase = atomicAdd(counter, sm[255]);
  __syncthreads();
  int excl = sm[tid] - d;
  if (n < N_NODES) {
    int o = sbase + excl;
    offs[n] = o;
    cursor[n] = o;
    deg[n] = d;
  }
}

__global__ __launch_bounds__(256) void k_scatter(const int* __restrict__ ei, int* __restrict__ cursor,
                                                 int* __restrict__ csr, int* __restrict__ csr_dst) {
  int i = blockIdx.x * 256 + threadIdx.x;
  if (i < N_EDGES) {
    int d = ei[N_EDGES + i];
    int pos = atomicAdd(&cursor[d], 1);
    csr[pos] = ei[i];
    csr_dst[pos] = d;
  } else if (i < E_TOT) {
    int n = i - N_EDGES;
    int pos = atomicAdd(&cursor[n], 1);
    csr[pos] = n;  // self loop
    csr_dst[pos] = n;
  }
}

// ---------------- bf16 MFMA GEMM: out[M,N] = A[M,K] @ Wt[N,K]^T ----------------

#define LDA 40

__global__ __launch_bounds__(256) void k_gemm_bf16(const unsigned short* __restrict__ A,
                                                   const unsigned short* __restrict__ Wt,
                                                   unsigned short* __restrict__ out, int M, int K, int Ncol) {
  __shared__ unsigned short As[128 * LDA];
  __shared__ unsigned short Bs[128 * LDA];
  int tid = threadIdx.x;
  int wave = tid >> 6, lane = tid & 63;
  int quad = lane >> 4, l16 = lane & 15;
  int wrow = (wave & 1) * 64, wcol = (wave >> 1) * 64;
  int row0 = blockIdx.x * 128, col0 = blockIdx.y * 128;

  float4v acc[4][4];
#pragma unroll
  for (int i = 0; i < 4; i++)
#pragma unroll
    for (int j = 0; j < 4; j++) acc[i][j] = (float4v)(0.f);

  int r0 = tid >> 2, c0 = (tid & 3) * 8;
  int r1 = (tid + 256) >> 2, c1 = c0;

  for (int k0 = 0; k0 < K; k0 += 32) {
    uint4 a0 = make_uint4(0, 0, 0, 0), a1 = make_uint4(0, 0, 0, 0);
    if (row0 + r0 < M) a0 = *(const uint4*)(A + (size_t)(row0 + r0) * K + k0 + c0);
    if (row0 + r1 < M) a1 = *(const uint4*)(A + (size_t)(row0 + r1) * K + k0 + c1);
    uint4 b0 = *(const uint4*)(Wt + (size_t)(col0 + r0) * K + k0 + c0);
    uint4 b1 = *(const uint4*)(Wt + (size_t)(col0 + r1) * K + k0 + c1);
    __syncthreads();
    *(uint4*)(&As[r0 * LDA + c0]) = a0;
    *(uint4*)(&As[r1 * LDA + c1]) = a1;
    *(uint4*)(&Bs[r0 * LDA + c0]) = b0;
    *(uint4*)(&Bs[r1 * LDA + c1]) = b1;
    __syncthreads();

    short8v af[4], bf[4];
#pragma unroll
    for (int i = 0; i < 4; i++)
      af[i] = *(const short8v*)(&As[(wrow + i * 16 + l16) * LDA + quad * 8]);
#pragma unroll
    for (int j = 0; j < 4; j++)
      bf[j] = *(const short8v*)(&Bs[(wcol + j * 16 + l16) * LDA + quad * 8]);
#pragma unroll
    for (int i = 0; i < 4; i++)
#pragma unroll
      for (int j = 0; j < 4; j++)
        acc[i][j] = __builtin_amdgcn_mfma_f32_16x16x32_bf16(af[i], bf[j], acc[i][j], 0, 0, 0);
  }

#pragma unroll
  for (int i = 0; i < 4; i++) {
#pragma unroll
    for (int r = 0; r < 4; r++) {
      int m = row0 + wrow + i * 16 + quad * 4 + r;
      if (m < M) {
#pragma unroll
        for (int j = 0; j < 4; j++) {
          int col = col0 + wcol + j * 16 + l16;
          out[(size_t)m * Ncol + col] = f2b(acc[i][j][r]);
        }
      }
    }
  }
}

// ---------------- attention logits (bf16 h, fp32 a) ----------------

template <int H, int C>
__global__ __launch_bounds__(256) void k_att(const unsigned short* __restrict__ hbuf,
                                             const float* __restrict__ a_s, const float* __restrict__ a_d,
                                             float* __restrict__ es, float* __restrict__ ed) {
  int idx = blockIdx.x * 256 + threadIdx.x;
  if (idx >= N_NODES * H) return;
  int n = idx / H;
  int h = idx % H;
  const unsigned short* row = hbuf + (size_t)n * (H * C) + h * C;
  const float* asp = a_s + h * C;
  const float* adp = a_d + h * C;
  float s = 0.f, d = 0.f;
#pragma unroll
  for (int c = 0; c < C; c += 8) {
    uint4 u = *(const uint4*)(row + c);
    float4 s0 = *(const float4*)(asp + c);
    float4 s1 = *(const float4*)(asp + c + 4);
    float4 d0 = *(const float4*)(adp + c);
    float4 d1 = *(const float4*)(adp + c + 4);
    float v0 = b2f((unsigned short)(u.x & 0xffff)), v1 = b2f((unsigned short)(u.x >> 16));
    float v2 = b2f((unsigned short)(u.y & 0xffff)), v3 = b2f((unsigned short)(u.y >> 16));
    float v4 = b2f((unsigned short)(u.z & 0xffff)), v5 = b2f((unsigned short)(u.z >> 16));
    float v6 = b2f((unsigned short)(u.w & 0xffff)), v7 = b2f((unsigned short)(u.w >> 16));
    s += v0 * s0.x + v1 * s0.y + v2 * s0.z + v3 * s0.w + v4 * s1.x + v5 * s1.y + v6 * s1.z + v7 * s1.w;
    d += v0 * d0.x + v1 * d0.y + v2 * d0.z + v3 * d0.w + v4 * d1.x + v5 * d1.y + v6 * d1.z + v7 * d1.w;
  }
  es[idx] = s;
  ed[idx] = d;
}

// ---------------- edge logits (CSR-ordered, edge-parallel) ----------------
// ew[pos][h] = leaky_relu(es[src][h] + ed[dst][h])

template <int H>
__global__ __launch_bounds__(256) void k_edge_logits(const float* __restrict__ es, const float* __restrict__ ed,
                                                     const int* __restrict__ csr, const int* __restrict__ csr_dst,
                                                     float* __restrict__ ew) {
  int p = blockIdx.x * 256 + threadIdx.x;
  if (p >= E_TOT) return;
  int s = csr[p], d = csr_dst[p];
  if (H == 4) {
    float4 a = *(const float4*)(es + (size_t)s * 4);
    float4 b = *(const float4*)(ed + (size_t)d * 4);
    float4 e;
    e.x = a.x + b.x; e.x = e.x > 0.f ? e.x : 0.2f * e.x;
    e.y = a.y + b.y; e.y = e.y > 0.f ? e.y : 0.2f * e.y;
    e.z = a.z + b.z; e.z = e.z > 0.f ? e.z : 0.2f * e.z;
    e.w = a.w + b.w; e.w = e.w > 0.f ? e.w : 0.2f * e.w;
    *(float4*)(ew + (size_t)p * 4) = e;
  } else {
    float e = es[s] + ed[d];
    ew[p] = e > 0.f ? e : 0.2f * e;
  }
}

// ---------------- softmax + aggregation ----------------
// One wave per dst node. Pass 1: max over contiguous ew. Pass 2: fused denom +
// accumulate, unrolled x4 so 4 independent feature gathers are in flight.

__device__ __forceinline__ void acc4(float* acc, float w, uint2 u) {
  acc[0] += w * b2f((unsigned short)(u.x & 0xffff));
  acc[1] += w * b2f((unsigned short)(u.x >> 16));
  acc[2] += w * b2f((unsigned short)(u.y & 0xffff));
  acc[3] += w * b2f((unsigned short)(u.y >> 16));
}
__device__ __forceinline__ void acc2(float* acc, float w, unsigned int u) {
  acc[0] += w * b2f((unsigned short)(u & 0xffff));
  acc[1] += w * b2f((unsigned short)(u >> 16));
}

template <int H, int C>
__global__ __launch_bounds__(256) void k_aggregate(const unsigned short* __restrict__ hbuf,
                                                   const float* __restrict__ ew, const int* __restrict__ offs,
                                                   const int* __restrict__ deg, const int* __restrict__ csr,
                                                   const float* __restrict__ bias,
                                                   unsigned short* __restrict__ out, int applyElu) {
  constexpr int F = H * C;
  constexpr int VPL = F / 64;  // 4 (H=4,C=64) or 2 (H=1,C=128)
  int wave = threadIdx.x >> 6;
  int lane = threadIdx.x & 63;
  int n = blockIdx.x * 4 + wave;
  if (n >= N_NODES) return;
  int head = (H == 1) ? 0 : (lane >> 4);
  int start = offs[n];
  int cnt = deg[n];
  const float* ewp = ew + (size_t)start * H + head;
  const int* csrp = csr + start;

  float m = -1e30f;
  for (int i = 0; i < cnt; i++) m = fmaxf(m, ewp[(size_t)i * H]);

  float denom = 0.f;
  float acc[VPL];
#pragma unroll
  for (int j = 0; j < VPL; j++) acc[j] = 0.f;

  int i = 0;
  for (; i + 4 <= cnt; i += 4) {
    int s0 = csrp[i], s1 = csrp[i + 1], s2 = csrp[i + 2], s3 = csrp[i + 3];
    float w0 = __expf(ewp[(size_t)(i + 0) * H] - m);
    float w1 = __expf(ewp[(size_t)(i + 1) * H] - m);
    float w2 = __expf(ewp[(size_t)(i + 2) * H] - m);
    float w3 = __expf(ewp[(size_t)(i + 3) * H] - m);
    denom += (w0 + w1) + (w2 + w3);
    if (VPL == 4) {
      uint2 u0 = *(const uint2*)(hbuf + (size_t)s0 * F + lane * 4);
      uint2 u1 = *(const uint2*)(hbuf + (size_t)s1 * F + lane * 4);
      uint2 u2 = *(const uint2*)(hbuf + (size_t)s2 * F + lane * 4);
      uint2 u3 = *(const uint2*)(hbuf + (size_t)s3 * F + lane * 4);
      acc4(acc, w0, u0); acc4(acc, w1, u1); acc4(acc, w2, u2); acc4(acc, w3, u3);
    } else {
      unsigned int u0 = *(const unsigned int*)(hbuf + (size_t)s0 * F + lane * 2);
      unsigned int u1 = *(const unsigned int*)(hbuf + (size_t)s1 * F + lane * 2);
      unsigned int u2 = *(const unsigned int*)(hbuf + (size_t)s2 * F + lane * 2);
      unsigned int u3 = *(const unsigned int*)(hbuf + (size_t)s3 * F + lane * 2);
      acc2(acc, w0, u0); acc2(acc, w1, u1); acc2(acc, w2, u2); acc2(acc, w3, u3);
    }
  }
  for (; i < cnt; i++) {
    int s = csrp[i];
    float w = __expf(ewp[(size_t)i * H] - m);
    denom += w;
    if (VPL == 4) {
      uint2 u = *(const uint2*)(hbuf + (size_t)s * F + lane * 4);
      acc4(acc, w, u);
    } else {
      unsigned int u = *(const unsigned int*)(hbuf + (size_t)s * F + lane * 2);
      acc2(acc, w, u);
    }
  }
  float inv = 1.0f / fmaxf(denom, 1e-16f);

  unsigned short ob[VPL];
#pragma unroll
  for (int j = 0; j < VPL; j++) {
    float v = acc[j] * inv + bias[lane * VPL + j];
    if (applyElu) v = v > 0.f ? v : expm1f(v);
    ob[j] = f2b(v);
  }
  if (VPL == 4) {
    ushort4 o = make_ushort4(ob[0], ob[1], ob[2], ob[3]);
    *(ushort4*)(out + (size_t)n * F + lane * 4) = o;
  } else {
    ushort2 o = make_ushort2(ob[0], ob[1]);
    *(ushort2*)(out + (size_t)n * F + lane * 2) = o;
  }
}

// ---------------- per-graph mean pool ----------------

__global__ __launch_bounds__(256) void k_pool(const unsigned short* __restrict__ feat,
                                              const int* __restrict__ batch, float* __restrict__ pool,
                                              float* __restrict__ cnt) {
  int wave = threadIdx.x >> 6;
  int lane = threadIdx.x & 63;
  int n = blockIdx.x * 4 + wave;
  if (n >= N_NODES) return;
  int g = batch[n];
  unsigned int u = *(const unsigned int*)(feat + (size_t)n * 128 + lane * 2);
  atomicAdd(&pool[g * 128 + lane * 2 + 0], b2f((unsigned short)(u & 0xffff)));
  atomicAdd(&pool[g * 128 + lane * 2 + 1], b2f((unsigned short)(u >> 16)));
  if (lane == 0) atomicAdd(&cnt[g], 1.0f);
}

// ---------------- MLP readout: 128 -> 64 -> 32 -> 4 ----------------

__global__ __launch_bounds__(128) void k_readout(const float* __restrict__ pool, const float* __restrict__ cnt,
                                                 const float* __restrict__ mW0, const float* __restrict__ mb0,
                                                 const float* __restrict__ mW1, const float* __restrict__ mb1,
                                                 const float* __restrict__ mW2, const float* __restrict__ mb2,
                                                 float* __restrict__ out) {
  __shared__ float p[128];
  __shared__ float y1[64];
  __shared__ float y2[32];
  int g = blockIdx.x;
  int t = threadIdx.x;
  float invc = 1.0f / fmaxf(cnt[g], 1.0f);
  p[t] = pool[(size_t)g * 128 + t] * invc;
  __syncthreads();
  if (t < 64) {
    float a = mb0[t];
#pragma unroll 4
    for (int k = 0; k < 128; k++) a += p[k] * mW0[k * 64 + t];
    y1[t] = a > 0.f ? a : 0.f;
  }
  __syncthreads();
  if (t < 32) {
    float a = mb1[t];
#pragma unroll 4
    for (int k = 0; k < 64; k++) a += y1[k] * mW1[k * 32 + t];
    y2[t] = a > 0.f ? a : 0.f;
  }
  __syncthreads();
  if (t < 4) {
    float a = mb2[t];
#pragma unroll 4
    for (int k = 0; k < 32; k++) a += y2[k] * mW2[k * 4 + t];
    out[(size_t)g * 4 + t] = a;
  }
}

// ---------------- host side ----------------

extern "C" void kernel_launch(void* const* d_in, const int* in_sizes, int n_in,
                              void* d_out, int out_size, void* d_ws, size_t ws_size,
                              hipStream_t stream) {
  const float* x = (const float*)d_in[0];
  const int* ei = (const int*)d_in[1];
  const int* batch = (const int*)d_in[2];
  const float* W0 = (const float*)d_in[4];
  const float* as0 = (const float*)d_in[5];
  const float* ad0 = (const float*)d_in[6];
  const float* b0 = (const float*)d_in[7];
  const float* W1 = (const float*)d_in[8];
  const float* as1 = (const float*)d_in[9];
  const float* ad1 = (const float*)d_in[10];
  const float* b1 = (const float*)d_in[11];
  const float* W2 = (const float*)d_in[12];
  const float* as2 = (const float*)d_in[13];
  const float* ad2 = (const float*)d_in[14];
  const float* b2 = (const float*)d_in[15];
  const float* W3 = (const float*)d_in[16];
  const float* as3 = (const float*)d_in[17];
  const float* ad3 = (const float*)d_in[18];
  const float* b3 = (const float*)d_in[19];
  const float* mW0 = (const float*)d_in[20];
  const float* mb0 = (const float*)d_in[21];
  const float* mW1 = (const float*)d_in[22];
  const float* mb1 = (const float*)d_in[23];
  const float* mW2 = (const float*)d_in[24];
  const float* mb2 = (const float*)d_in[25];
  float* out = (float*)d_out;

  char* ws = (char*)d_ws;
  size_t cur = 0;
  auto alloc = [&](size_t bytes) -> char* {
    char* p = ws + cur;
    cur += (bytes + 255) & ~(size_t)255;
    return p;
  };
  unsigned short* featA = (unsigned short*)alloc((size_t)N_NODES * 256 * 2);
  unsigned short* hB = (unsigned short*)alloc((size_t)N_NODES * 256 * 2);
  unsigned short* xb = (unsigned short*)alloc((size_t)N_NODES * 64 * 2);
  unsigned short* wt0 = (unsigned short*)alloc((size_t)256 * 64 * 2);
  unsigned short* wt1 = (unsigned short*)alloc((size_t)256 * 256 * 2);
  unsigned short* wt2 = (unsigned short*)alloc((size_t)256 * 256 * 2);
  unsigned short* wt3 = (unsigned short*)alloc((size_t)128 * 256 * 2);
  float* es = (float*)alloc((size_t)N_NODES * 4 * sizeof(float));
  float* ed = (float*)alloc((size_t)N_NODES * 4 * sizeof(float));
  float* ew = (float*)alloc((size_t)E_TOT * 4 * sizeof(float));
  int* deg = (int*)alloc((size_t)N_NODES * sizeof(int));
  int* offs = (int*)alloc((size_t)N_NODES * sizeof(int));
  int* cursor = (int*)alloc((size_t)N_NODES * sizeof(int));
  int* csr = (int*)alloc((size_t)E_TOT * sizeof(int));
  int* csr_dst = (int*)alloc((size_t)E_TOT * sizeof(int));
  float* pool = (float*)alloc((size_t)N_GRAPHS_C * 128 * sizeof(float));
  float* cnt = (float*)alloc((size_t)N_GRAPHS_C * sizeof(float));
  int* counter = (int*)alloc(256);
  (void)ws_size; (void)in_sizes; (void)n_in; (void)out_size;

  // ---- conversions ----
  k_cvt_x<<<ceil_div(N_NODES * 64 / 4, 256), 256, 0, stream>>>(x, xb, N_NODES * 64 / 4);
  k_cvt_wt<<<ceil_div(64 * 256, 256), 256, 0, stream>>>(W0, wt0, 64, 256);
  k_cvt_wt<<<ceil_div(256 * 256, 256), 256, 0, stream>>>(W1, wt1, 256, 256);
  k_cvt_wt<<<ceil_div(256 * 256, 256), 256, 0, stream>>>(W2, wt2, 256, 256);
  k_cvt_wt<<<ceil_div(256 * 128, 256), 256, 0, stream>>>(W3, wt3, 256, 128);

  // ---- CSR build ----
  hipMemsetAsync(deg, 0, (size_t)N_NODES * sizeof(int), stream);
  hipMemsetAsync(counter, 0, sizeof(int), stream);
  k_count_deg<<<ceil_div(N_EDGES, 256), 256, 0, stream>>>(ei, deg);
  k_scan<<<ceil_div(N_NODES, 256), 256, 0, stream>>>(deg, offs, cursor, counter);
  k_scatter<<<ceil_div(E_TOT, 256), 256, 0, stream>>>(ei, cursor, csr, csr_dst);

  int gm = ceil_div(N_NODES, 128);
  dim3 g256(gm, 2), g128(gm, 1);
  int aggBlocks = ceil_div(N_NODES, 4);
  int edgeBlocks = ceil_div(E_TOT, 256);

  // ---- layer 0: 64 -> 4x64 ----
  k_gemm_bf16<<<g256, 256, 0, stream>>>(xb, wt0, hB, N_NODES, 64, 256);
  k_att<4, 64><<<ceil_div(N_NODES * 4, 256), 256, 0, stream>>>(hB, as0, ad0, es, ed);
  k_edge_logits<4><<<edgeBlocks, 256, 0, stream>>>(es, ed, csr, csr_dst, ew);
  k_aggregate<4, 64><<<aggBlocks, 256, 0, stream>>>(hB, ew, offs, deg, csr, b0, featA, 1);

  // ---- layer 1 ----
  k_gemm_bf16<<<g256, 256, 0, stream>>>(featA, wt1, hB, N_NODES, 256, 256);
  k_att<4, 64><<<ceil_div(N_NODES * 4, 256), 256, 0, stream>>>(hB, as1, ad1, es, ed);
  k_edge_logits<4><<<edgeBlocks, 256, 0, stream>>>(es, ed, csr, csr_dst, ew);
  k_aggregate<4, 64><<<aggBlocks, 256, 0, stream>>>(hB, ew, offs, deg, csr, b1, featA, 1);

  // ---- layer 2 ----
  k_gemm_bf16<<<g256, 256, 0, stream>>>(featA, wt2, hB, N_NODES, 256, 256);
  k_att<4, 64><<<ceil_div(N_NODES * 4, 256), 256, 0, stream>>>(hB, as2, ad2, es, ed);
  k_edge_logits<4><<<edgeBlocks, 256, 0, stream>>>(es, ed, csr, csr_dst, ew);
  k_aggregate<4, 64><<<aggBlocks, 256, 0, stream>>>(hB, ew, offs, deg, csr, b2, featA, 1);

  // ---- layer 3: 256 -> 128, 1 head, no ELU ----
  k_gemm_bf16<<<g128, 256, 0, stream>>>(featA, wt3, hB, N_NODES, 256, 128);
  k_att<1, 128><<<ceil_div(N_NODES, 256), 256, 0, stream>>>(hB, as3, ad3, es, ed);
  k_edge_logits<1><<<edgeBlocks, 256, 0, stream>>>(es, ed, csr, csr_dst, ew);
  k_aggregate<1, 128><<<aggBlocks, 256, 0, stream>>>(hB, ew, offs, deg, csr, b3, featA, 0);

  // ---- pool + readout ----
  hipMemsetAsync(pool, 0, (size_t)N_GRAPHS_C * 128 * sizeof(float), stream);
  hipMemsetAsync(cnt, 0, (size_t)N_GRAPHS_C * sizeof(float), stream);
  k_pool<<<aggBlocks, 256, 0, stream>>>(featA, batch, pool, cnt);
  k_readout<<<N_GRAPHS_C, 128, 0, stream>>>(pool, cnt, mW0, mb0, mW1, mb1, mW2, mb2, out);
}

// Round 4
// 764.434 us; speedup vs baseline: 2.1234x; 1.0880x over previous
//
#include <hip/hip_runtime.h>
#include <math.h>

#define N_NODES 100000
#define N_EDGES 400000
#define N_GRAPHS_C 4096
#define E_TOT (N_EDGES + N_NODES)

static inline int ceil_div(int a, int b) { return (a + b - 1) / b; }

typedef __attribute__((ext_vector_type(8))) short short8v;
typedef __attribute__((ext_vector_type(4))) float float4v;

__device__ __forceinline__ float b2f(unsigned short u) {
  union { unsigned int i; float f; } v;
  v.i = ((unsigned int)u) << 16;
  return v.f;
}
__device__ __forceinline__ unsigned short f2b(float f) {
  union { float f; unsigned int i; } v;
  v.f = f;
  unsigned int x = v.i;
  unsigned int r = x + 0x7fffu + ((x >> 16) & 1u);  // RNE
  return (unsigned short)(r >> 16);
}

// ---------------- dtype conversion ----------------

__global__ __launch_bounds__(256) void k_cvt_x(const float* __restrict__ in, unsigned short* __restrict__ out,
                                               int n4) {
  int i = blockIdx.x * 256 + threadIdx.x;
  if (i >= n4) return;
  float4 v = *(const float4*)(in + (size_t)i * 4);
  ushort4 o;
  o.x = f2b(v.x); o.y = f2b(v.y); o.z = f2b(v.z); o.w = f2b(v.w);
  *(ushort4*)(out + (size_t)i * 4) = o;
}

// W[K,N] fp32 -> Wt[N,K] bf16
__global__ __launch_bounds__(256) void k_cvt_wt(const float* __restrict__ W, unsigned short* __restrict__ Wt,
                                                int K, int Ncol) {
  int i = blockIdx.x * 256 + threadIdx.x;
  if (i >= K * Ncol) return;
  int n = i / K, k = i % K;
  Wt[(size_t)n * K + k] = f2b(W[(size_t)k * Ncol + n]);
}

// ---------------- CSR build ----------------

__global__ __launch_bounds__(256) void k_count_deg(const int* __restrict__ ei, int* __restrict__ deg) {
  int i = blockIdx.x * 256 + threadIdx.x;
  if (i < N_EDGES) atomicAdd(&deg[ei[N_EDGES + i]], 1);
}

__global__ __launch_bounds__(256) void k_scan(int* __restrict__ deg, int* __restrict__ offs,
                                              int* __restrict__ cursor, int* __restrict__ counter) {
  __shared__ int sm[256];
  __shared__ int sbase;
  int tid = threadIdx.x;
  int n = blockIdx.x * 256 + tid;
  int d = (n < N_NODES) ? (deg[n] + 1) : 0;  // +1 self loop
  sm[tid] = d;
  __syncthreads();
  for (int off = 1; off < 256; off <<= 1) {
    int v = (tid >= off) ? sm[tid - off] : 0;
    __syncthreads();
    sm[tid] += v;
    __syncthreads();
  }
  if (tid == 255) sbase = atomicAdd(counter, sm[255]);
  __syncthreads();
  int excl = sm[tid] - d;
  if (n < N_NODES) {
    int o = sbase + excl;
    offs[n] = o;
    cursor[n] = o;
    deg[n] = d;
  }
}

__global__ __launch_bounds__(256) void k_scatter(const int* __restrict__ ei, int* __restrict__ cursor,
                                                 int* __restrict__ csr, int* __restrict__ csr_dst) {
  int i = blockIdx.x * 256 + threadIdx.x;
  if (i < N_EDGES) {
    int d = ei[N_EDGES + i];
    int pos = atomicAdd(&cursor[d], 1);
    csr[pos] = ei[i];
    csr_dst[pos] = d;
  } else if (i < E_TOT) {
    int n = i - N_EDGES;
    int pos = atomicAdd(&cursor[n], 1);
    csr[pos] = n;  // self loop
    csr_dst[pos] = n;
  }
}

// ---------------- graph segment build (batch is sorted) ----------------

__global__ __launch_bounds__(256) void k_gcount(const int* __restrict__ batch, int* __restrict__ gcnt) {
  int i = blockIdx.x * 256 + threadIdx.x;
  if (i < N_NODES) atomicAdd(&gcnt[batch[i]], 1);
}

// single block, 256 threads: exclusive scan of gcnt[4096] -> gptr
__global__ __launch_bounds__(256) void k_gscan(const int* __restrict__ gcnt, int* __restrict__ gptr) {
  __shared__ int sm[256];
  __shared__ int srun;
  int tid = threadIdx.x;
  if (tid == 0) srun = 0;
  __syncthreads();
  for (int c = 0; c < N_GRAPHS_C / 256; c++) {
    int idx = c * 256 + tid;
    int v = gcnt[idx];
    sm[tid] = v;
    __syncthreads();
    for (int off = 1; off < 256; off <<= 1) {
      int t = (tid >= off) ? sm[tid - off] : 0;
      __syncthreads();
      sm[tid] += t;
      __syncthreads();
    }
    gptr[idx] = srun + sm[tid] - v;
    __syncthreads();
    if (tid == 0) srun += sm[255];
    __syncthreads();
  }
}

// ---------------- bf16 MFMA GEMM: out[M,N] = A[M,K] @ Wt[N,K]^T ----------------

#define LDA 40

__global__ __launch_bounds__(256) void k_gemm_bf16(const unsigned short* __restrict__ A,
                                                   const unsigned short* __restrict__ Wt,
                                                   unsigned short* __restrict__ out, int M, int K, int Ncol) {
  __shared__ unsigned short As[128 * LDA];
  __shared__ unsigned short Bs[128 * LDA];
  int tid = threadIdx.x;
  int wave = tid >> 6, lane = tid & 63;
  int quad = lane >> 4, l16 = lane & 15;
  int wrow = (wave & 1) * 64, wcol = (wave >> 1) * 64;
  int row0 = blockIdx.x * 128, col0 = blockIdx.y * 128;

  float4v acc[4][4];
#pragma unroll
  for (int i = 0; i < 4; i++)
#pragma unroll
    for (int j = 0; j < 4; j++) acc[i][j] = (float4v)(0.f);

  int r0 = tid >> 2, c0 = (tid & 3) * 8;
  int r1 = (tid + 256) >> 2, c1 = c0;

  for (int k0 = 0; k0 < K; k0 += 32) {
    uint4 a0 = make_uint4(0, 0, 0, 0), a1 = make_uint4(0, 0, 0, 0);
    if (row0 + r0 < M) a0 = *(const uint4*)(A + (size_t)(row0 + r0) * K + k0 + c0);
    if (row0 + r1 < M) a1 = *(const uint4*)(A + (size_t)(row0 + r1) * K + k0 + c1);
    uint4 b0 = *(const uint4*)(Wt + (size_t)(col0 + r0) * K + k0 + c0);
    uint4 b1 = *(const uint4*)(Wt + (size_t)(col0 + r1) * K + k0 + c1);
    __syncthreads();
    *(uint4*)(&As[r0 * LDA + c0]) = a0;
    *(uint4*)(&As[r1 * LDA + c1]) = a1;
    *(uint4*)(&Bs[r0 * LDA + c0]) = b0;
    *(uint4*)(&Bs[r1 * LDA + c1]) = b1;
    __syncthreads();

    short8v af[4], bf[4];
#pragma unroll
    for (int i = 0; i < 4; i++)
      af[i] = *(const short8v*)(&As[(wrow + i * 16 + l16) * LDA + quad * 8]);
#pragma unroll
    for (int j = 0; j < 4; j++)
      bf[j] = *(const short8v*)(&Bs[(wcol + j * 16 + l16) * LDA + quad * 8]);
#pragma unroll
    for (int i = 0; i < 4; i++)
#pragma unroll
      for (int j = 0; j < 4; j++)
        acc[i][j] = __builtin_amdgcn_mfma_f32_16x16x32_bf16(af[i], bf[j], acc[i][j], 0, 0, 0);
  }

#pragma unroll
  for (int i = 0; i < 4; i++) {
#pragma unroll
    for (int r = 0; r < 4; r++) {
      int m = row0 + wrow + i * 16 + quad * 4 + r;
      if (m < M) {
#pragma unroll
        for (int j = 0; j < 4; j++) {
          int col = col0 + wcol + j * 16 + l16;
          out[(size_t)m * Ncol + col] = f2b(acc[i][j][r]);
        }
      }
    }
  }
}

// ---------------- attention logits (bf16 h, fp32 a) ----------------

template <int H, int C>
__global__ __launch_bounds__(256) void k_att(const unsigned short* __restrict__ hbuf,
                                             const float* __restrict__ a_s, const float* __restrict__ a_d,
                                             float* __restrict__ es, float* __restrict__ ed) {
  int idx = blockIdx.x * 256 + threadIdx.x;
  if (idx >= N_NODES * H) return;
  int n = idx / H;
  int h = idx % H;
  const unsigned short* row = hbuf + (size_t)n * (H * C) + h * C;
  const float* asp = a_s + h * C;
  const float* adp = a_d + h * C;
  float s = 0.f, d = 0.f;
#pragma unroll
  for (int c = 0; c < C; c += 8) {
    uint4 u = *(const uint4*)(row + c);
    float4 s0 = *(const float4*)(asp + c);
    float4 s1 = *(const float4*)(asp + c + 4);
    float4 d0 = *(const float4*)(adp + c);
    float4 d1 = *(const float4*)(adp + c + 4);
    float v0 = b2f((unsigned short)(u.x & 0xffff)), v1 = b2f((unsigned short)(u.x >> 16));
    float v2 = b2f((unsigned short)(u.y & 0xffff)), v3 = b2f((unsigned short)(u.y >> 16));
    float v4 = b2f((unsigned short)(u.z & 0xffff)), v5 = b2f((unsigned short)(u.z >> 16));
    float v6 = b2f((unsigned short)(u.w & 0xffff)), v7 = b2f((unsigned short)(u.w >> 16));
    s += v0 * s0.x + v1 * s0.y + v2 * s0.z + v3 * s0.w + v4 * s1.x + v5 * s1.y + v6 * s1.z + v7 * s1.w;
    d += v0 * d0.x + v1 * d0.y + v2 * d0.z + v3 * d0.w + v4 * d1.x + v5 * d1.y + v6 * d1.z + v7 * d1.w;
  }
  es[idx] = s;
  ed[idx] = d;
}

// ---------------- edge logits (CSR-ordered, edge-parallel) ----------------

template <int H>
__global__ __launch_bounds__(256) void k_edge_logits(const float* __restrict__ es, const float* __restrict__ ed,
                                                     const int* __restrict__ csr, const int* __restrict__ csr_dst,
                                                     float* __restrict__ ew) {
  int p = blockIdx.x * 256 + threadIdx.x;
  if (p >= E_TOT) return;
  int s = csr[p], d = csr_dst[p];
  if (H == 4) {
    float4 a = *(const float4*)(es + (size_t)s * 4);
    float4 b = *(const float4*)(ed + (size_t)d * 4);
    float4 e;
    e.x = a.x + b.x; e.x = e.x > 0.f ? e.x : 0.2f * e.x;
    e.y = a.y + b.y; e.y = e.y > 0.f ? e.y : 0.2f * e.y;
    e.z = a.z + b.z; e.z = e.z > 0.f ? e.z : 0.2f * e.z;
    e.w = a.w + b.w; e.w = e.w > 0.f ? e.w : 0.2f * e.w;
    *(float4*)(ew + (size_t)p * 4) = e;
  } else {
    float e = es[s] + ed[d];
    ew[p] = e > 0.f ? e : 0.2f * e;
  }
}

// ---------------- softmax + aggregation ----------------

__device__ __forceinline__ void acc4(float* acc, float w, uint2 u) {
  acc[0] += w * b2f((unsigned short)(u.x & 0xffff));
  acc[1] += w * b2f((unsigned short)(u.x >> 16));
  acc[2] += w * b2f((unsigned short)(u.y & 0xffff));
  acc[3] += w * b2f((unsigned short)(u.y >> 16));
}
__device__ __forceinline__ void acc2(float* acc, float w, unsigned int u) {
  acc[0] += w * b2f((unsigned short)(u & 0xffff));
  acc[1] += w * b2f((unsigned short)(u >> 16));
}

template <int H, int C>
__global__ __launch_bounds__(256) void k_aggregate(const unsigned short* __restrict__ hbuf,
                                                   const float* __restrict__ ew, const int* __restrict__ offs,
                                                   const int* __restrict__ deg, const int* __restrict__ csr,
                                                   const float* __restrict__ bias,
                                                   unsigned short* __restrict__ out, int applyElu) {
  constexpr int F = H * C;
  constexpr int VPL = F / 64;  // 4 (H=4,C=64) or 2 (H=1,C=128)
  int wave = threadIdx.x >> 6;
  int lane = threadIdx.x & 63;
  int n = blockIdx.x * 4 + wave;
  if (n >= N_NODES) return;
  int head = (H == 1) ? 0 : (lane >> 4);
  int start = offs[n];
  int cnt = deg[n];
  const float* ewp = ew + (size_t)start * H + head;
  const int* csrp = csr + start;

  float m = -1e30f;
  for (int i = 0; i < cnt; i++) m = fmaxf(m, ewp[(size_t)i * H]);

  float denom = 0.f;
  float acc[VPL];
#pragma unroll
  for (int j = 0; j < VPL; j++) acc[j] = 0.f;

  int i = 0;
  for (; i + 4 <= cnt; i += 4) {
    int s0 = csrp[i], s1 = csrp[i + 1], s2 = csrp[i + 2], s3 = csrp[i + 3];
    float w0 = __expf(ewp[(size_t)(i + 0) * H] - m);
    float w1 = __expf(ewp[(size_t)(i + 1) * H] - m);
    float w2 = __expf(ewp[(size_t)(i + 2) * H] - m);
    float w3 = __expf(ewp[(size_t)(i + 3) * H] - m);
    denom += (w0 + w1) + (w2 + w3);
    if (VPL == 4) {
      uint2 u0 = *(const uint2*)(hbuf + (size_t)s0 * F + lane * 4);
      uint2 u1 = *(const uint2*)(hbuf + (size_t)s1 * F + lane * 4);
      uint2 u2 = *(const uint2*)(hbuf + (size_t)s2 * F + lane * 4);
      uint2 u3 = *(const uint2*)(hbuf + (size_t)s3 * F + lane * 4);
      acc4(acc, w0, u0); acc4(acc, w1, u1); acc4(acc, w2, u2); acc4(acc, w3, u3);
    } else {
      unsigned int u0 = *(const unsigned int*)(hbuf + (size_t)s0 * F + lane * 2);
      unsigned int u1 = *(const unsigned int*)(hbuf + (size_t)s1 * F + lane * 2);
      unsigned int u2 = *(const unsigned int*)(hbuf + (size_t)s2 * F + lane * 2);
      unsigned int u3 = *(const unsigned int*)(hbuf + (size_t)s3 * F + lane * 2);
      acc2(acc, w0, u0); acc2(acc, w1, u1); acc2(acc, w2, u2); acc2(acc, w3, u3);
    }
  }
  for (; i < cnt; i++) {
    int s = csrp[i];
    float w = __expf(ewp[(size_t)i * H] - m);
    denom += w;
    if (VPL == 4) {
      uint2 u = *(const uint2*)(hbuf + (size_t)s * F + lane * 4);
      acc4(acc, w, u);
    } else {
      unsigned int u = *(const unsigned int*)(hbuf + (size_t)s * F + lane * 2);
      acc2(acc, w, u);
    }
  }
  float inv = 1.0f / fmaxf(denom, 1e-16f);

  unsigned short ob[VPL];
#pragma unroll
  for (int j = 0; j < VPL; j++) {
    float v = acc[j] * inv + bias[lane * VPL + j];
    if (applyElu) v = v > 0.f ? v : expm1f(v);
    ob[j] = f2b(v);
  }
  if (VPL == 4) {
    ushort4 o = make_ushort4(ob[0], ob[1], ob[2], ob[3]);
    *(ushort4*)(out + (size_t)n * F + lane * 4) = o;
  } else {
    ushort2 o = make_ushort2(ob[0], ob[1]);
    *(ushort2*)(out + (size_t)n * F + lane * 2) = o;
  }
}

// ---------------- per-graph mean pool (segmented, batch sorted) ----------------
// One wave per graph; lane owns channels lane*2, lane*2+1; writes the MEAN.

__global__ __launch_bounds__(256) void k_pool_seg(const unsigned short* __restrict__ feat,
                                                  const int* __restrict__ gptr, const int* __restrict__ gcnt,
                                                  float* __restrict__ pool) {
  int wave = threadIdx.x >> 6;
  int lane = threadIdx.x & 63;
  int g = blockIdx.x * 4 + wave;
  if (g >= N_GRAPHS_C) return;
  int start = gptr[g];
  int c = gcnt[g];
  float a0 = 0.f, a1 = 0.f;
  int i = 0;
  for (; i + 2 <= c; i += 2) {
    unsigned int u0 = *(const unsigned int*)(feat + (size_t)(start + i) * 128 + lane * 2);
    unsigned int u1 = *(const unsigned int*)(feat + (size_t)(start + i + 1) * 128 + lane * 2);
    a0 += b2f((unsigned short)(u0 & 0xffff)) + b2f((unsigned short)(u1 & 0xffff));
    a1 += b2f((unsigned short)(u0 >> 16)) + b2f((unsigned short)(u1 >> 16));
  }
  if (i < c) {
    unsigned int u = *(const unsigned int*)(feat + (size_t)(start + i) * 128 + lane * 2);
    a0 += b2f((unsigned short)(u & 0xffff));
    a1 += b2f((unsigned short)(u >> 16));
  }
  float invc = 1.0f / fmaxf((float)c, 1.0f);
  pool[(size_t)g * 128 + lane * 2 + 0] = a0 * invc;
  pool[(size_t)g * 128 + lane * 2 + 1] = a1 * invc;
}

// ---------------- MLP readout: 128 -> 64 -> 32 -> 4 ----------------

__global__ __launch_bounds__(128) void k_readout(const float* __restrict__ pool,
                                                 const float* __restrict__ mW0, const float* __restrict__ mb0,
                                                 const float* __restrict__ mW1, const float* __restrict__ mb1,
                                                 const float* __restrict__ mW2, const float* __restrict__ mb2,
                                                 float* __restrict__ out) {
  __shared__ float p[128];
  __shared__ float y1[64];
  __shared__ float y2[32];
  int g = blockIdx.x;
  int t = threadIdx.x;
  p[t] = pool[(size_t)g * 128 + t];
  __syncthreads();
  if (t < 64) {
    float a = mb0[t];
#pragma unroll 4
    for (int k = 0; k < 128; k++) a += p[k] * mW0[k * 64 + t];
    y1[t] = a > 0.f ? a : 0.f;
  }
  __syncthreads();
  if (t < 32) {
    float a = mb1[t];
#pragma unroll 4
    for (int k = 0; k < 64; k++) a += y1[k] * mW1[k * 32 + t];
    y2[t] = a > 0.f ? a : 0.f;
  }
  __syncthreads();
  if (t < 4) {
    float a = mb2[t];
#pragma unroll 4
    for (int k = 0; k < 32; k++) a += y2[k] * mW2[k * 4 + t];
    out[(size_t)g * 4 + t] = a;
  }
}

// ---------------- host side ----------------

extern "C" void kernel_launch(void* const* d_in, const int* in_sizes, int n_in,
                              void* d_out, int out_size, void* d_ws, size_t ws_size,
                              hipStream_t stream) {
  const float* x = (const float*)d_in[0];
  const int* ei = (const int*)d_in[1];
  const int* batch = (const int*)d_in[2];
  const float* W0 = (const float*)d_in[4];
  const float* as0 = (const float*)d_in[5];
  const float* ad0 = (const float*)d_in[6];
  const float* b0 = (const float*)d_in[7];
  const float* W1 = (const float*)d_in[8];
  const float* as1 = (const float*)d_in[9];
  const float* ad1 = (const float*)d_in[10];
  const float* b1 = (const float*)d_in[11];
  const float* W2 = (const float*)d_in[12];
  const float* as2 = (const float*)d_in[13];
  const float* ad2 = (const float*)d_in[14];
  const float* b2 = (const float*)d_in[15];
  const float* W3 = (const float*)d_in[16];
  const float* as3 = (const float*)d_in[17];
  const float* ad3 = (const float*)d_in[18];
  const float* b3 = (const float*)d_in[19];
  const float* mW0 = (const float*)d_in[20];
  const float* mb0 = (const float*)d_in[21];
  const float* mW1 = (const float*)d_in[22];
  const float* mb1 = (const float*)d_in[23];
  const float* mW2 = (const float*)d_in[24];
  const float* mb2 = (const float*)d_in[25];
  float* out = (float*)d_out;

  char* ws = (char*)d_ws;
  size_t cur = 0;
  auto alloc = [&](size_t bytes) -> char* {
    char* p = ws + cur;
    cur += (bytes + 255) & ~(size_t)255;
    return p;
  };
  unsigned short* featA = (unsigned short*)alloc((size_t)N_NODES * 256 * 2);
  unsigned short* hB = (unsigned short*)alloc((size_t)N_NODES * 256 * 2);
  unsigned short* xb = (unsigned short*)alloc((size_t)N_NODES * 64 * 2);
  unsigned short* wt0 = (unsigned short*)alloc((size_t)256 * 64 * 2);
  unsigned short* wt1 = (unsigned short*)alloc((size_t)256 * 256 * 2);
  unsigned short* wt2 = (unsigned short*)alloc((size_t)256 * 256 * 2);
  unsigned short* wt3 = (unsigned short*)alloc((size_t)128 * 256 * 2);
  float* es = (float*)alloc((size_t)N_NODES * 4 * sizeof(float));
  float* ed = (float*)alloc((size_t)N_NODES * 4 * sizeof(float));
  float* ew = (float*)alloc((size_t)E_TOT * 4 * sizeof(float));
  int* deg = (int*)alloc((size_t)N_NODES * sizeof(int));
  int* offs = (int*)alloc((size_t)N_NODES * sizeof(int));
  int* cursor = (int*)alloc((size_t)N_NODES * sizeof(int));
  int* csr = (int*)alloc((size_t)E_TOT * sizeof(int));
  int* csr_dst = (int*)alloc((size_t)E_TOT * sizeof(int));
  float* pool = (float*)alloc((size_t)N_GRAPHS_C * 128 * sizeof(float));
  int* gcnt = (int*)alloc((size_t)N_GRAPHS_C * sizeof(int));
  int* gptr = (int*)alloc((size_t)N_GRAPHS_C * sizeof(int));
  int* counter = (int*)alloc(256);
  (void)ws_size; (void)in_sizes; (void)n_in; (void)out_size;

  // ---- conversions ----
  k_cvt_x<<<ceil_div(N_NODES * 64 / 4, 256), 256, 0, stream>>>(x, xb, N_NODES * 64 / 4);
  k_cvt_wt<<<ceil_div(64 * 256, 256), 256, 0, stream>>>(W0, wt0, 64, 256);
  k_cvt_wt<<<ceil_div(256 * 256, 256), 256, 0, stream>>>(W1, wt1, 256, 256);
  k_cvt_wt<<<ceil_div(256 * 256, 256), 256, 0, stream>>>(W2, wt2, 256, 256);
  k_cvt_wt<<<ceil_div(256 * 128, 256), 256, 0, stream>>>(W3, wt3, 256, 128);

  // ---- CSR build + graph segments ----
  hipMemsetAsync(deg, 0, (size_t)N_NODES * sizeof(int), stream);
  hipMemsetAsync(counter, 0, sizeof(int), stream);
  hipMemsetAsync(gcnt, 0, (size_t)N_GRAPHS_C * sizeof(int), stream);
  k_count_deg<<<ceil_div(N_EDGES, 256), 256, 0, stream>>>(ei, deg);
  k_scan<<<ceil_div(N_NODES, 256), 256, 0, stream>>>(deg, offs, cursor, counter);
  k_scatter<<<ceil_div(E_TOT, 256), 256, 0, stream>>>(ei, cursor, csr, csr_dst);
  k_gcount<<<ceil_div(N_NODES, 256), 256, 0, stream>>>(batch, gcnt);
  k_gscan<<<1, 256, 0, stream>>>(gcnt, gptr);

  int gm = ceil_div(N_NODES, 128);
  dim3 g256(gm, 2), g128(gm, 1);
  int aggBlocks = ceil_div(N_NODES, 4);
  int edgeBlocks = ceil_div(E_TOT, 256);

  // ---- layer 0: 64 -> 4x64 ----
  k_gemm_bf16<<<g256, 256, 0, stream>>>(xb, wt0, hB, N_NODES, 64, 256);
  k_att<4, 64><<<ceil_div(N_NODES * 4, 256), 256, 0, stream>>>(hB, as0, ad0, es, ed);
  k_edge_logits<4><<<edgeBlocks, 256, 0, stream>>>(es, ed, csr, csr_dst, ew);
  k_aggregate<4, 64><<<aggBlocks, 256, 0, stream>>>(hB, ew, offs, deg, csr, b0, featA, 1);

  // ---- layer 1 ----
  k_gemm_bf16<<<g256, 256, 0, stream>>>(featA, wt1, hB, N_NODES, 256, 256);
  k_att<4, 64><<<ceil_div(N_NODES * 4, 256), 256, 0, stream>>>(hB, as1, ad1, es, ed);
  k_edge_logits<4><<<edgeBlocks, 256, 0, stream>>>(es, ed, csr, csr_dst, ew);
  k_aggregate<4, 64><<<aggBlocks, 256, 0, stream>>>(hB, ew, offs, deg, csr, b1, featA, 1);

  // ---- layer 2 ----
  k_gemm_bf16<<<g256, 256, 0, stream>>>(featA, wt2, hB, N_NODES, 256, 256);
  k_att<4, 64><<<ceil_div(N_NODES * 4, 256), 256, 0, stream>>>(hB, as2, ad2, es, ed);
  k_edge_logits<4><<<edgeBlocks, 256, 0, stream>>>(es, ed, csr, csr_dst, ew);
  k_aggregate<4, 64><<<aggBlocks, 256, 0, stream>>>(hB, ew, offs, deg, csr, b2, featA, 1);

  // ---- layer 3: 256 -> 128, 1 head, no ELU ----
  k_gemm_bf16<<<g128, 256, 0, stream>>>(featA, wt3, hB, N_NODES, 256, 128);
  k_att<1, 128><<<ceil_div(N_NODES, 256), 256, 0, stream>>>(hB, as3, ad3, es, ed);
  k_edge_logits<1><<<edgeBlocks, 256, 0, stream>>>(es, ed, csr, csr_dst, ew);
  k_aggregate<1, 128><<<aggBlocks, 256, 0, stream>>>(hB, ew, offs, deg, csr, b3, featA, 0);

  // ---- pool + readout ----
  k_pool_seg<<<ceil_div(N_GRAPHS_C, 4), 256, 0, stream>>>(featA, gptr, gcnt, pool);
  k_readout<<<N_GRAPHS_C, 128, 0, stream>>>(pool, mW0, mb0, mW1, mb1, mW2, mb2, out);
}

// Round 5
// 734.943 us; speedup vs baseline: 2.2086x; 1.0401x over previous
//
#include <hip/hip_runtime.h>
#include <math.h>

#define N_NODES 100000
#define N_EDGES 400000
#define N_GRAPHS_C 4096
#define E_TOT (N_EDGES + N_NODES)

static inline int ceil_div(int a, int b) { return (a + b - 1) / b; }

typedef __attribute__((ext_vector_type(8))) short short8v;
typedef __attribute__((ext_vector_type(4))) float float4v;

__device__ __forceinline__ float b2f(unsigned short u) {
  union { unsigned int i; float f; } v;
  v.i = ((unsigned int)u) << 16;
  return v.f;
}
__device__ __forceinline__ unsigned short f2b(float f) {
  union { float f; unsigned int i; } v;
  v.f = f;
  unsigned int x = v.i;
  unsigned int r = x + 0x7fffu + ((x >> 16) & 1u);  // RNE
  return (unsigned short)(r >> 16);
}

// ---------------- dtype conversion ----------------

__global__ __launch_bounds__(256) void k_cvt_x(const float* __restrict__ in, unsigned short* __restrict__ out,
                                               int n4) {
  int i = blockIdx.x * 256 + threadIdx.x;
  if (i >= n4) return;
  float4 v = *(const float4*)(in + (size_t)i * 4);
  ushort4 o;
  o.x = f2b(v.x); o.y = f2b(v.y); o.z = f2b(v.z); o.w = f2b(v.w);
  *(ushort4*)(out + (size_t)i * 4) = o;
}

// W[K,N] fp32 -> Wt[N,K] bf16
__global__ __launch_bounds__(256) void k_cvt_wt(const float* __restrict__ W, unsigned short* __restrict__ Wt,
                                                int K, int Ncol) {
  int i = blockIdx.x * 256 + threadIdx.x;
  if (i >= K * Ncol) return;
  int n = i / K, k = i % K;
  Wt[(size_t)n * K + k] = f2b(W[(size_t)k * Ncol + n]);
}

// ---------------- CSR build ----------------

__global__ __launch_bounds__(256) void k_count_deg(const int* __restrict__ ei, int* __restrict__ deg) {
  int i = blockIdx.x * 256 + threadIdx.x;
  if (i < N_EDGES) atomicAdd(&deg[ei[N_EDGES + i]], 1);
}

__global__ __launch_bounds__(256) void k_scan(int* __restrict__ deg, int* __restrict__ offs,
                                              int* __restrict__ cursor, int* __restrict__ counter) {
  __shared__ int sm[256];
  __shared__ int sbase;
  int tid = threadIdx.x;
  int n = blockIdx.x * 256 + tid;
  int d = (n < N_NODES) ? (deg[n] + 1) : 0;  // +1 self loop
  sm[tid] = d;
  __syncthreads();
  for (int off = 1; off < 256; off <<= 1) {
    int v = (tid >= off) ? sm[tid - off] : 0;
    __syncthreads();
    sm[tid] += v;
    __syncthreads();
  }
  if (tid == 255) sbase = atomicAdd(counter, sm[255]);
  __syncthreads();
  int excl = sm[tid] - d;
  if (n < N_NODES) {
    int o = sbase + excl;
    offs[n] = o;
    cursor[n] = o;
    deg[n] = d;
  }
}

__global__ __launch_bounds__(256) void k_scatter(const int* __restrict__ ei, int* __restrict__ cursor,
                                                 int* __restrict__ csr, int* __restrict__ csr_dst) {
  int i = blockIdx.x * 256 + threadIdx.x;
  if (i < N_EDGES) {
    int d = ei[N_EDGES + i];
    int pos = atomicAdd(&cursor[d], 1);
    csr[pos] = ei[i];
    csr_dst[pos] = d;
  } else if (i < E_TOT) {
    int n = i - N_EDGES;
    int pos = atomicAdd(&cursor[n], 1);
    csr[pos] = n;  // self loop
    csr_dst[pos] = n;
  }
}

// ---------------- graph segment build (batch is sorted) ----------------

__global__ __launch_bounds__(256) void k_gcount(const int* __restrict__ batch, int* __restrict__ gcnt) {
  int i = blockIdx.x * 256 + threadIdx.x;
  if (i < N_NODES) atomicAdd(&gcnt[batch[i]], 1);
}

__global__ __launch_bounds__(256) void k_gscan(const int* __restrict__ gcnt, int* __restrict__ gptr) {
  __shared__ int sm[256];
  __shared__ int srun;
  int tid = threadIdx.x;
  if (tid == 0) srun = 0;
  __syncthreads();
  for (int c = 0; c < N_GRAPHS_C / 256; c++) {
    int idx = c * 256 + tid;
    int v = gcnt[idx];
    sm[tid] = v;
    __syncthreads();
    for (int off = 1; off < 256; off <<= 1) {
      int t = (tid >= off) ? sm[tid - off] : 0;
      __syncthreads();
      sm[tid] += t;
      __syncthreads();
    }
    gptr[idx] = srun + sm[tid] - v;
    __syncthreads();
    if (tid == 0) srun += sm[255];
    __syncthreads();
  }
}

// ---------------- bf16 MFMA GEMM: out[M,N] = A[M,K] @ Wt[N,K]^T ----------------

#define LDA 40

__global__ __launch_bounds__(256) void k_gemm_bf16(const unsigned short* __restrict__ A,
                                                   const unsigned short* __restrict__ Wt,
                                                   unsigned short* __restrict__ out, int M, int K, int Ncol) {
  __shared__ unsigned short As[128 * LDA];
  __shared__ unsigned short Bs[128 * LDA];
  int tid = threadIdx.x;
  int wave = tid >> 6, lane = tid & 63;
  int quad = lane >> 4, l16 = lane & 15;
  int wrow = (wave & 1) * 64, wcol = (wave >> 1) * 64;
  int row0 = blockIdx.x * 128, col0 = blockIdx.y * 128;

  float4v acc[4][4];
#pragma unroll
  for (int i = 0; i < 4; i++)
#pragma unroll
    for (int j = 0; j < 4; j++) acc[i][j] = (float4v)(0.f);

  int r0 = tid >> 2, c0 = (tid & 3) * 8;
  int r1 = (tid + 256) >> 2, c1 = c0;

  for (int k0 = 0; k0 < K; k0 += 32) {
    uint4 a0 = make_uint4(0, 0, 0, 0), a1 = make_uint4(0, 0, 0, 0);
    if (row0 + r0 < M) a0 = *(const uint4*)(A + (size_t)(row0 + r0) * K + k0 + c0);
    if (row0 + r1 < M) a1 = *(const uint4*)(A + (size_t)(row0 + r1) * K + k0 + c1);
    uint4 b0 = *(const uint4*)(Wt + (size_t)(col0 + r0) * K + k0 + c0);
    uint4 b1 = *(const uint4*)(Wt + (size_t)(col0 + r1) * K + k0 + c1);
    __syncthreads();
    *(uint4*)(&As[r0 * LDA + c0]) = a0;
    *(uint4*)(&As[r1 * LDA + c1]) = a1;
    *(uint4*)(&Bs[r0 * LDA + c0]) = b0;
    *(uint4*)(&Bs[r1 * LDA + c1]) = b1;
    __syncthreads();

    short8v af[4], bf[4];
#pragma unroll
    for (int i = 0; i < 4; i++)
      af[i] = *(const short8v*)(&As[(wrow + i * 16 + l16) * LDA + quad * 8]);
#pragma unroll
    for (int j = 0; j < 4; j++)
      bf[j] = *(const short8v*)(&Bs[(wcol + j * 16 + l16) * LDA + quad * 8]);
#pragma unroll
    for (int i = 0; i < 4; i++)
#pragma unroll
      for (int j = 0; j < 4; j++)
        acc[i][j] = __builtin_amdgcn_mfma_f32_16x16x32_bf16(af[i], bf[j], acc[i][j], 0, 0, 0);
  }

#pragma unroll
  for (int i = 0; i < 4; i++) {
#pragma unroll
    for (int r = 0; r < 4; r++) {
      int m = row0 + wrow + i * 16 + quad * 4 + r;
      if (m < M) {
#pragma unroll
        for (int j = 0; j < 4; j++) {
          int col = col0 + wcol + j * 16 + l16;
          out[(size_t)m * Ncol + col] = f2b(acc[i][j][r]);
        }
      }
    }
  }
}

// ---------------- attention logits (bf16 h, fp32 a) ----------------

template <int H, int C>
__global__ __launch_bounds__(256) void k_att(const unsigned short* __restrict__ hbuf,
                                             const float* __restrict__ a_s, const float* __restrict__ a_d,
                                             float* __restrict__ es, float* __restrict__ ed) {
  int idx = blockIdx.x * 256 + threadIdx.x;
  if (idx >= N_NODES * H) return;
  int n = idx / H;
  int h = idx % H;
  const unsigned short* row = hbuf + (size_t)n * (H * C) + h * C;
  const float* asp = a_s + h * C;
  const float* adp = a_d + h * C;
  float s = 0.f, d = 0.f;
#pragma unroll
  for (int c = 0; c < C; c += 8) {
    uint4 u = *(const uint4*)(row + c);
    float4 s0 = *(const float4*)(asp + c);
    float4 s1 = *(const float4*)(asp + c + 4);
    float4 d0 = *(const float4*)(adp + c);
    float4 d1 = *(const float4*)(adp + c + 4);
    float v0 = b2f((unsigned short)(u.x & 0xffff)), v1 = b2f((unsigned short)(u.x >> 16));
    float v2 = b2f((unsigned short)(u.y & 0xffff)), v3 = b2f((unsigned short)(u.y >> 16));
    float v4 = b2f((unsigned short)(u.z & 0xffff)), v5 = b2f((unsigned short)(u.z >> 16));
    float v6 = b2f((unsigned short)(u.w & 0xffff)), v7 = b2f((unsigned short)(u.w >> 16));
    s += v0 * s0.x + v1 * s0.y + v2 * s0.z + v3 * s0.w + v4 * s1.x + v5 * s1.y + v6 * s1.z + v7 * s1.w;
    d += v0 * d0.x + v1 * d0.y + v2 * d0.z + v3 * d0.w + v4 * d1.x + v5 * d1.y + v6 * d1.z + v7 * d1.w;
  }
  es[idx] = s;
  ed[idx] = d;
}

// ---------------- edge logits (CSR-ordered, edge-parallel) ----------------

template <int H>
__global__ __launch_bounds__(256) void k_edge_logits(const float* __restrict__ es, const float* __restrict__ ed,
                                                     const int* __restrict__ csr, const int* __restrict__ csr_dst,
                                                     float* __restrict__ ew) {
  int p = blockIdx.x * 256 + threadIdx.x;
  if (p >= E_TOT) return;
  int s = csr[p], d = csr_dst[p];
  if (H == 4) {
    float4 a = *(const float4*)(es + (size_t)s * 4);
    float4 b = *(const float4*)(ed + (size_t)d * 4);
    float4 e;
    e.x = a.x + b.x; e.x = e.x > 0.f ? e.x : 0.2f * e.x;
    e.y = a.y + b.y; e.y = e.y > 0.f ? e.y : 0.2f * e.y;
    e.z = a.z + b.z; e.z = e.z > 0.f ? e.z : 0.2f * e.z;
    e.w = a.w + b.w; e.w = e.w > 0.f ? e.w : 0.2f * e.w;
    *(float4*)(ew + (size_t)p * 4) = e;
  } else {
    float e = es[s] + ed[d];
    ew[p] = e > 0.f ? e : 0.2f * e;
  }
}

// ---------------- softmax stats: per (node,head) max + 1/denom ----------------
// Contiguous reads of ew; massive TLP hides the short serial loops.

template <int H>
__global__ __launch_bounds__(256) void k_stats(const float* __restrict__ ew, const int* __restrict__ offs,
                                               const int* __restrict__ deg, float2* __restrict__ stats) {
  int idx = blockIdx.x * 256 + threadIdx.x;
  if (idx >= N_NODES * H) return;
  int n = (H == 1) ? idx : (idx >> 2);
  int h = (H == 1) ? 0 : (idx & 3);
  const float* p = ew + (size_t)offs[n] * H + h;
  int c = deg[n];
  float m = -1e30f;
  for (int i = 0; i < c; i++) m = fmaxf(m, p[(size_t)i * H]);
  float s = 0.f;
  for (int i = 0; i < c; i++) s += __expf(p[(size_t)i * H] - m);
  float2 o;
  o.x = m;
  o.y = 1.0f / fmaxf(s, 1e-16f);
  stats[idx] = o;
}

// ---------------- aggregation (lean: gather + FMA only) ----------------

__device__ __forceinline__ void acc4(float* acc, float w, uint2 u) {
  acc[0] += w * b2f((unsigned short)(u.x & 0xffff));
  acc[1] += w * b2f((unsigned short)(u.x >> 16));
  acc[2] += w * b2f((unsigned short)(u.y & 0xffff));
  acc[3] += w * b2f((unsigned short)(u.y >> 16));
}
__device__ __forceinline__ void acc2(float* acc, float w, unsigned int u) {
  acc[0] += w * b2f((unsigned short)(u & 0xffff));
  acc[1] += w * b2f((unsigned short)(u >> 16));
}

template <int H, int C>
__global__ __launch_bounds__(256) void k_aggregate(const unsigned short* __restrict__ hbuf,
                                                   const float* __restrict__ ew,
                                                   const float2* __restrict__ stats,
                                                   const int* __restrict__ offs, const int* __restrict__ deg,
                                                   const int* __restrict__ csr, const float* __restrict__ bias,
                                                   unsigned short* __restrict__ out, int applyElu) {
  constexpr int F = H * C;
  constexpr int VPL = F / 64;  // 4 (H=4,C=64) or 2 (H=1,C=128)
  int wave = threadIdx.x >> 6;
  int lane = threadIdx.x & 63;
  int n = blockIdx.x * 4 + wave;
  if (n >= N_NODES) return;
  int head = (H == 1) ? 0 : (lane >> 4);
  int start = offs[n];
  int cnt = deg[n];
  const float* ewp = ew + (size_t)start * H + head;
  const int* csrp = csr + start;
  float2 st = stats[n * H + head];
  float m = st.x, inv = st.y;

  float acc[VPL];
#pragma unroll
  for (int j = 0; j < VPL; j++) acc[j] = 0.f;

  int i = 0;
  for (; i + 4 <= cnt; i += 4) {
    int s0 = csrp[i], s1 = csrp[i + 1], s2 = csrp[i + 2], s3 = csrp[i + 3];
    float w0 = __expf(ewp[(size_t)(i + 0) * H] - m);
    float w1 = __expf(ewp[(size_t)(i + 1) * H] - m);
    float w2 = __expf(ewp[(size_t)(i + 2) * H] - m);
    float w3 = __expf(ewp[(size_t)(i + 3) * H] - m);
    if (VPL == 4) {
      uint2 u0 = *(const uint2*)(hbuf + (size_t)s0 * F + lane * 4);
      uint2 u1 = *(const uint2*)(hbuf + (size_t)s1 * F + lane * 4);
      uint2 u2 = *(const uint2*)(hbuf + (size_t)s2 * F + lane * 4);
      uint2 u3 = *(const uint2*)(hbuf + (size_t)s3 * F + lane * 4);
      acc4(acc, w0, u0); acc4(acc, w1, u1); acc4(acc, w2, u2); acc4(acc, w3, u3);
    } else {
      unsigned int u0 = *(const unsigned int*)(hbuf + (size_t)s0 * F + lane * 2);
      unsigned int u1 = *(const unsigned int*)(hbuf + (size_t)s1 * F + lane * 2);
      unsigned int u2 = *(const unsigned int*)(hbuf + (size_t)s2 * F + lane * 2);
      unsigned int u3 = *(const unsigned int*)(hbuf + (size_t)s3 * F + lane * 2);
      acc2(acc, w0, u0); acc2(acc, w1, u1); acc2(acc, w2, u2); acc2(acc, w3, u3);
    }
  }
  for (; i < cnt; i++) {
    int s = csrp[i];
    float w = __expf(ewp[(size_t)i * H] - m);
    if (VPL == 4) {
      uint2 u = *(const uint2*)(hbuf + (size_t)s * F + lane * 4);
      acc4(acc, w, u);
    } else {
      unsigned int u = *(const unsigned int*)(hbuf + (size_t)s * F + lane * 2);
      acc2(acc, w, u);
    }
  }

  unsigned short ob[VPL];
#pragma unroll
  for (int j = 0; j < VPL; j++) {
    float v = acc[j] * inv + bias[lane * VPL + j];
    if (applyElu) v = v > 0.f ? v : expm1f(v);
    ob[j] = f2b(v);
  }
  if (VPL == 4) {
    ushort4 o = make_ushort4(ob[0], ob[1], ob[2], ob[3]);
    *(ushort4*)(out + (size_t)n * F + lane * 4) = o;
  } else {
    ushort2 o = make_ushort2(ob[0], ob[1]);
    *(ushort2*)(out + (size_t)n * F + lane * 2) = o;
  }
}

// ---------------- per-graph mean pool (segmented, batch sorted) ----------------

__global__ __launch_bounds__(256) void k_pool_seg(const unsigned short* __restrict__ feat,
                                                  const int* __restrict__ gptr, const int* __restrict__ gcnt,
                                                  float* __restrict__ pool) {
  int wave = threadIdx.x >> 6;
  int lane = threadIdx.x & 63;
  int g = blockIdx.x * 4 + wave;
  if (g >= N_GRAPHS_C) return;
  int start = gptr[g];
  int c = gcnt[g];
  float a0 = 0.f, a1 = 0.f;
  int i = 0;
  for (; i + 2 <= c; i += 2) {
    unsigned int u0 = *(const unsigned int*)(feat + (size_t)(start + i) * 128 + lane * 2);
    unsigned int u1 = *(const unsigned int*)(feat + (size_t)(start + i + 1) * 128 + lane * 2);
    a0 += b2f((unsigned short)(u0 & 0xffff)) + b2f((unsigned short)(u1 & 0xffff));
    a1 += b2f((unsigned short)(u0 >> 16)) + b2f((unsigned short)(u1 >> 16));
  }
  if (i < c) {
    unsigned int u = *(const unsigned int*)(feat + (size_t)(start + i) * 128 + lane * 2);
    a0 += b2f((unsigned short)(u & 0xffff));
    a1 += b2f((unsigned short)(u >> 16));
  }
  float invc = 1.0f / fmaxf((float)c, 1.0f);
  pool[(size_t)g * 128 + lane * 2 + 0] = a0 * invc;
  pool[(size_t)g * 128 + lane * 2 + 1] = a1 * invc;
}

// ---------------- MLP readout: 128 -> 64 -> 32 -> 4 ----------------

__global__ __launch_bounds__(128) void k_readout(const float* __restrict__ pool,
                                                 const float* __restrict__ mW0, const float* __restrict__ mb0,
                                                 const float* __restrict__ mW1, const float* __restrict__ mb1,
                                                 const float* __restrict__ mW2, const float* __restrict__ mb2,
                                                 float* __restrict__ out) {
  __shared__ float p[128];
  __shared__ float y1[64];
  __shared__ float y2[32];
  int g = blockIdx.x;
  int t = threadIdx.x;
  p[t] = pool[(size_t)g * 128 + t];
  __syncthreads();
  if (t < 64) {
    float a = mb0[t];
#pragma unroll 4
    for (int k = 0; k < 128; k++) a += p[k] * mW0[k * 64 + t];
    y1[t] = a > 0.f ? a : 0.f;
  }
  __syncthreads();
  if (t < 32) {
    float a = mb1[t];
#pragma unroll 4
    for (int k = 0; k < 64; k++) a += y1[k] * mW1[k * 32 + t];
    y2[t] = a > 0.f ? a : 0.f;
  }
  __syncthreads();
  if (t < 4) {
    float a = mb2[t];
#pragma unroll 4
    for (int k = 0; k < 32; k++) a += y2[k] * mW2[k * 4 + t];
    out[(size_t)g * 4 + t] = a;
  }
}

// ---------------- host side ----------------

extern "C" void kernel_launch(void* const* d_in, const int* in_sizes, int n_in,
                              void* d_out, int out_size, void* d_ws, size_t ws_size,
                              hipStream_t stream) {
  const float* x = (const float*)d_in[0];
  const int* ei = (const int*)d_in[1];
  const int* batch = (const int*)d_in[2];
  const float* W0 = (const float*)d_in[4];
  const float* as0 = (const float*)d_in[5];
  const float* ad0 = (const float*)d_in[6];
  const float* b0 = (const float*)d_in[7];
  const float* W1 = (const float*)d_in[8];
  const float* as1 = (const float*)d_in[9];
  const float* ad1 = (const float*)d_in[10];
  const float* b1 = (const float*)d_in[11];
  const float* W2 = (const float*)d_in[12];
  const float* as2 = (const float*)d_in[13];
  const float* ad2 = (const float*)d_in[14];
  const float* b2 = (const float*)d_in[15];
  const float* W3 = (const float*)d_in[16];
  const float* as3 = (const float*)d_in[17];
  const float* ad3 = (const float*)d_in[18];
  const float* b3 = (const float*)d_in[19];
  const float* mW0 = (const float*)d_in[20];
  const float* mb0 = (const float*)d_in[21];
  const float* mW1 = (const float*)d_in[22];
  const float* mb1 = (const float*)d_in[23];
  const float* mW2 = (const float*)d_in[24];
  const float* mb2 = (const float*)d_in[25];
  float* out = (float*)d_out;

  char* ws = (char*)d_ws;
  size_t cur = 0;
  auto alloc = [&](size_t bytes) -> char* {
    char* p = ws + cur;
    cur += (bytes + 255) & ~(size_t)255;
    return p;
  };
  unsigned short* featA = (unsigned short*)alloc((size_t)N_NODES * 256 * 2);
  unsigned short* hB = (unsigned short*)alloc((size_t)N_NODES * 256 * 2);
  unsigned short* xb = (unsigned short*)alloc((size_t)N_NODES * 64 * 2);
  unsigned short* wt0 = (unsigned short*)alloc((size_t)256 * 64 * 2);
  unsigned short* wt1 = (unsigned short*)alloc((size_t)256 * 256 * 2);
  unsigned short* wt2 = (unsigned short*)alloc((size_t)256 * 256 * 2);
  unsigned short* wt3 = (unsigned short*)alloc((size_t)128 * 256 * 2);
  float* es = (float*)alloc((size_t)N_NODES * 4 * sizeof(float));
  float* ed = (float*)alloc((size_t)N_NODES * 4 * sizeof(float));
  float* ew = (float*)alloc((size_t)E_TOT * 4 * sizeof(float));
  float2* stats = (float2*)alloc((size_t)N_NODES * 4 * sizeof(float2));
  int* deg = (int*)alloc((size_t)N_NODES * sizeof(int));
  int* offs = (int*)alloc((size_t)N_NODES * sizeof(int));
  int* cursor = (int*)alloc((size_t)N_NODES * sizeof(int));
  int* csr = (int*)alloc((size_t)E_TOT * sizeof(int));
  int* csr_dst = (int*)alloc((size_t)E_TOT * sizeof(int));
  float* pool = (float*)alloc((size_t)N_GRAPHS_C * 128 * sizeof(float));
  int* gcnt = (int*)alloc((size_t)N_GRAPHS_C * sizeof(int));
  int* gptr = (int*)alloc((size_t)N_GRAPHS_C * sizeof(int));
  int* counter = (int*)alloc(256);
  (void)ws_size; (void)in_sizes; (void)n_in; (void)out_size;

  // ---- conversions ----
  k_cvt_x<<<ceil_div(N_NODES * 64 / 4, 256), 256, 0, stream>>>(x, xb, N_NODES * 64 / 4);
  k_cvt_wt<<<ceil_div(64 * 256, 256), 256, 0, stream>>>(W0, wt0, 64, 256);
  k_cvt_wt<<<ceil_div(256 * 256, 256), 256, 0, stream>>>(W1, wt1, 256, 256);
  k_cvt_wt<<<ceil_div(256 * 256, 256), 256, 0, stream>>>(W2, wt2, 256, 256);
  k_cvt_wt<<<ceil_div(256 * 128, 256), 256, 0, stream>>>(W3, wt3, 256, 128);

  // ---- CSR build + graph segments ----
  hipMemsetAsync(deg, 0, (size_t)N_NODES * sizeof(int), stream);
  hipMemsetAsync(counter, 0, sizeof(int), stream);
  hipMemsetAsync(gcnt, 0, (size_t)N_GRAPHS_C * sizeof(int), stream);
  k_count_deg<<<ceil_div(N_EDGES, 256), 256, 0, stream>>>(ei, deg);
  k_scan<<<ceil_div(N_NODES, 256), 256, 0, stream>>>(deg, offs, cursor, counter);
  k_scatter<<<ceil_div(E_TOT, 256), 256, 0, stream>>>(ei, cursor, csr, csr_dst);
  k_gcount<<<ceil_div(N_NODES, 256), 256, 0, stream>>>(batch, gcnt);
  k_gscan<<<1, 256, 0, stream>>>(gcnt, gptr);

  int gm = ceil_div(N_NODES, 128);
  dim3 g256(gm, 2), g128(gm, 1);
  int aggBlocks = ceil_div(N_NODES, 4);
  int edgeBlocks = ceil_div(E_TOT, 256);
  int statBlocks4 = ceil_div(N_NODES * 4, 256);
  int statBlocks1 = ceil_div(N_NODES, 256);

  // ---- layer 0: 64 -> 4x64 ----
  k_gemm_bf16<<<g256, 256, 0, stream>>>(xb, wt0, hB, N_NODES, 64, 256);
  k_att<4, 64><<<statBlocks4, 256, 0, stream>>>(hB, as0, ad0, es, ed);
  k_edge_logits<4><<<edgeBlocks, 256, 0, stream>>>(es, ed, csr, csr_dst, ew);
  k_stats<4><<<statBlocks4, 256, 0, stream>>>(ew, offs, deg, stats);
  k_aggregate<4, 64><<<aggBlocks, 256, 0, stream>>>(hB, ew, stats, offs, deg, csr, b0, featA, 1);

  // ---- layer 1 ----
  k_gemm_bf16<<<g256, 256, 0, stream>>>(featA, wt1, hB, N_NODES, 256, 256);
  k_att<4, 64><<<statBlocks4, 256, 0, stream>>>(hB, as1, ad1, es, ed);
  k_edge_logits<4><<<edgeBlocks, 256, 0, stream>>>(es, ed, csr, csr_dst, ew);
  k_stats<4><<<statBlocks4, 256, 0, stream>>>(ew, offs, deg, stats);
  k_aggregate<4, 64><<<aggBlocks, 256, 0, stream>>>(hB, ew, stats, offs, deg, csr, b1, featA, 1);

  // ---- layer 2 ----
  k_gemm_bf16<<<g256, 256, 0, stream>>>(featA, wt2, hB, N_NODES, 256, 256);
  k_att<4, 64><<<statBlocks4, 256, 0, stream>>>(hB, as2, ad2, es, ed);
  k_edge_logits<4><<<edgeBlocks, 256, 0, stream>>>(es, ed, csr, csr_dst, ew);
  k_stats<4><<<statBlocks4, 256, 0, stream>>>(ew, offs, deg, stats);
  k_aggregate<4, 64><<<aggBlocks, 256, 0, stream>>>(hB, ew, stats, offs, deg, csr, b2, featA, 1);

  // ---- layer 3: 256 -> 128, 1 head, no ELU ----
  k_gemm_bf16<<<g128, 256, 0, stream>>>(featA, wt3, hB, N_NODES, 256, 128);
  k_att<1, 128><<<statBlocks1, 256, 0, stream>>>(hB, as3, ad3, es, ed);
  k_edge_logits<1><<<edgeBlocks, 256, 0, stream>>>(es, ed, csr, csr_dst, ew);
  k_stats<1><<<statBlocks1, 256, 0, stream>>>(ew, offs, deg, stats);
  k_aggregate<1, 128><<<aggBlocks, 256, 0, stream>>>(hB, ew, stats, offs, deg, csr, b3, featA, 0);

  // ---- pool + readout ----
  k_pool_seg<<<ceil_div(N_GRAPHS_C, 4), 256, 0, stream>>>(featA, gptr, gcnt, pool);
  k_readout<<<N_GRAPHS_C, 128, 0, stream>>>(pool, mW0, mb0, mW1, mb1, mW2, mb2, out);
}

// Round 6
// 675.988 us; speedup vs baseline: 2.4012x; 1.0872x over previous
//
#include <hip/hip_runtime.h>
#include <math.h>

#define N_NODES 100000
#define N_EDGES 400000
#define N_GRAPHS_C 4096
#define E_TOT (N_EDGES + N_NODES)

static inline int ceil_div(int a, int b) { return (a + b - 1) / b; }

typedef __attribute__((ext_vector_type(8))) short short8v;
typedef __attribute__((ext_vector_type(4))) float float4v;

__device__ __forceinline__ float b2f(unsigned short u) {
  union { unsigned int i; float f; } v;
  v.i = ((unsigned int)u) << 16;
  return v.f;
}
__device__ __forceinline__ unsigned short f2b(float f) {
  union { float f; unsigned int i; } v;
  v.f = f;
  unsigned int x = v.i;
  unsigned int r = x + 0x7fffu + ((x >> 16) & 1u);  // RNE
  return (unsigned short)(r >> 16);
}

// ---------------- dtype conversion ----------------

__global__ __launch_bounds__(256) void k_cvt_x(const float* __restrict__ in, unsigned short* __restrict__ out,
                                               int n4) {
  int i = blockIdx.x * 256 + threadIdx.x;
  if (i >= n4) return;
  float4 v = *(const float4*)(in + (size_t)i * 4);
  ushort4 o;
  o.x = f2b(v.x); o.y = f2b(v.y); o.z = f2b(v.z); o.w = f2b(v.w);
  *(ushort4*)(out + (size_t)i * 4) = o;
}

// W[K,N] fp32 -> Wt[N,K] bf16
__global__ __launch_bounds__(256) void k_cvt_wt(const float* __restrict__ W, unsigned short* __restrict__ Wt,
                                                int K, int Ncol) {
  int i = blockIdx.x * 256 + threadIdx.x;
  if (i >= K * Ncol) return;
  int n = i / K, k = i % K;
  Wt[(size_t)n * K + k] = f2b(W[(size_t)k * Ncol + n]);
}

// ---------------- CSR build ----------------

__global__ __launch_bounds__(256) void k_count_deg(const int* __restrict__ ei, int* __restrict__ deg) {
  int i = blockIdx.x * 256 + threadIdx.x;
  if (i < N_EDGES) atomicAdd(&deg[ei[N_EDGES + i]], 1);
}

__global__ __launch_bounds__(256) void k_scan(int* __restrict__ deg, int* __restrict__ offs,
                                              int* __restrict__ cursor, int* __restrict__ counter) {
  __shared__ int sm[256];
  __shared__ int sbase;
  int tid = threadIdx.x;
  int n = blockIdx.x * 256 + tid;
  int d = (n < N_NODES) ? (deg[n] + 1) : 0;  // +1 self loop
  sm[tid] = d;
  __syncthreads();
  for (int off = 1; off < 256; off <<= 1) {
    int v = (tid >= off) ? sm[tid - off] : 0;
    __syncthreads();
    sm[tid] += v;
    __syncthreads();
  }
  if (tid == 255) sbase = atomicAdd(counter, sm[255]);
  __syncthreads();
  int excl = sm[tid] - d;
  if (n < N_NODES) {
    int o = sbase + excl;
    offs[n] = o;
    cursor[n] = o;
    deg[n] = d;
  }
}

__global__ __launch_bounds__(256) void k_scatter(const int* __restrict__ ei, int* __restrict__ cursor,
                                                 int* __restrict__ csr, int* __restrict__ csr_dst) {
  int i = blockIdx.x * 256 + threadIdx.x;
  if (i < N_EDGES) {
    int d = ei[N_EDGES + i];
    int pos = atomicAdd(&cursor[d], 1);
    csr[pos] = ei[i];
    csr_dst[pos] = d;
  } else if (i < E_TOT) {
    int n = i - N_EDGES;
    int pos = atomicAdd(&cursor[n], 1);
    csr[pos] = n;  // self loop
    csr_dst[pos] = n;
  }
}

// ---------------- graph segment build (batch is sorted) ----------------

__global__ __launch_bounds__(256) void k_gcount(const int* __restrict__ batch, int* __restrict__ gcnt) {
  int i = blockIdx.x * 256 + threadIdx.x;
  if (i < N_NODES) atomicAdd(&gcnt[batch[i]], 1);
}

__global__ __launch_bounds__(256) void k_gscan(const int* __restrict__ gcnt, int* __restrict__ gptr) {
  __shared__ int sm[256];
  __shared__ int srun;
  int tid = threadIdx.x;
  if (tid == 0) srun = 0;
  __syncthreads();
  for (int c = 0; c < N_GRAPHS_C / 256; c++) {
    int idx = c * 256 + tid;
    int v = gcnt[idx];
    sm[tid] = v;
    __syncthreads();
    for (int off = 1; off < 256; off <<= 1) {
      int t = (tid >= off) ? sm[tid - off] : 0;
      __syncthreads();
      sm[tid] += t;
      __syncthreads();
    }
    gptr[idx] = srun + sm[tid] - v;
    __syncthreads();
    if (tid == 0) srun += sm[255];
    __syncthreads();
  }
}

// ---------------- bf16 MFMA GEMM: out[M,N] = A[M,K] @ Wt[N,K]^T ----------------
// ATT=1: fused attention-logit epilogue (H=4, C=64). Each wave owns one head's
// 64 columns; es/ed row-sums reduced across the 16-lane l16 group via shfl_xor.

#define LDA 40

template <int ATT>
__global__ __launch_bounds__(256) void k_gemm_bf16(const unsigned short* __restrict__ A,
                                                   const unsigned short* __restrict__ Wt,
                                                   unsigned short* __restrict__ out, int M, int K, int Ncol,
                                                   const float* __restrict__ a_s, const float* __restrict__ a_d,
                                                   float* __restrict__ es, float* __restrict__ ed) {
  __shared__ unsigned short As[128 * LDA];
  __shared__ unsigned short Bs[128 * LDA];
  int tid = threadIdx.x;
  int wave = tid >> 6, lane = tid & 63;
  int quad = lane >> 4, l16 = lane & 15;
  int wrow = (wave & 1) * 64, wcol = (wave >> 1) * 64;
  int row0 = blockIdx.x * 128, col0 = blockIdx.y * 128;

  float4v acc[4][4];
#pragma unroll
  for (int i = 0; i < 4; i++)
#pragma unroll
    for (int j = 0; j < 4; j++) acc[i][j] = (float4v)(0.f);

  int r0 = tid >> 2, c0 = (tid & 3) * 8;
  int r1 = (tid + 256) >> 2, c1 = c0;

  for (int k0 = 0; k0 < K; k0 += 32) {
    uint4 a0 = make_uint4(0, 0, 0, 0), a1 = make_uint4(0, 0, 0, 0);
    if (row0 + r0 < M) a0 = *(const uint4*)(A + (size_t)(row0 + r0) * K + k0 + c0);
    if (row0 + r1 < M) a1 = *(const uint4*)(A + (size_t)(row0 + r1) * K + k0 + c1);
    uint4 b0 = *(const uint4*)(Wt + (size_t)(col0 + r0) * K + k0 + c0);
    uint4 b1 = *(const uint4*)(Wt + (size_t)(col0 + r1) * K + k0 + c1);
    __syncthreads();
    *(uint4*)(&As[r0 * LDA + c0]) = a0;
    *(uint4*)(&As[r1 * LDA + c1]) = a1;
    *(uint4*)(&Bs[r0 * LDA + c0]) = b0;
    *(uint4*)(&Bs[r1 * LDA + c1]) = b1;
    __syncthreads();

    short8v af[4], bf[4];
#pragma unroll
    for (int i = 0; i < 4; i++)
      af[i] = *(const short8v*)(&As[(wrow + i * 16 + l16) * LDA + quad * 8]);
#pragma unroll
    for (int j = 0; j < 4; j++)
      bf[j] = *(const short8v*)(&Bs[(wcol + j * 16 + l16) * LDA + quad * 8]);
#pragma unroll
    for (int i = 0; i < 4; i++)
#pragma unroll
      for (int j = 0; j < 4; j++)
        acc[i][j] = __builtin_amdgcn_mfma_f32_16x16x32_bf16(af[i], bf[j], acc[i][j], 0, 0, 0);
  }

#pragma unroll
  for (int i = 0; i < 4; i++) {
#pragma unroll
    for (int r = 0; r < 4; r++) {
      int m = row0 + wrow + i * 16 + quad * 4 + r;
      if (m < M) {
#pragma unroll
        for (int j = 0; j < 4; j++) {
          int col = col0 + wcol + j * 16 + l16;
          out[(size_t)m * Ncol + col] = f2b(acc[i][j][r]);
        }
      }
    }
  }

  if (ATT) {
    int h = (col0 + wcol) >> 6;  // this wave's head
    float as_r[4], ad_r[4];
#pragma unroll
    for (int j = 0; j < 4; j++) {
      as_r[j] = a_s[h * 64 + j * 16 + l16];
      ad_r[j] = a_d[h * 64 + j * 16 + l16];
    }
#pragma unroll
    for (int i = 0; i < 4; i++) {
#pragma unroll
      for (int r = 0; r < 4; r++) {
        float pes = acc[i][0][r] * as_r[0] + acc[i][1][r] * as_r[1] + acc[i][2][r] * as_r[2] + acc[i][3][r] * as_r[3];
        float ped = acc[i][0][r] * ad_r[0] + acc[i][1][r] * ad_r[1] + acc[i][2][r] * ad_r[2] + acc[i][3][r] * ad_r[3];
#pragma unroll
        for (int mk = 1; mk < 16; mk <<= 1) {
          pes += __shfl_xor(pes, mk, 64);
          ped += __shfl_xor(ped, mk, 64);
        }
        if (l16 == 0) {
          int m = row0 + wrow + i * 16 + quad * 4 + r;
          if (m < M) {
            es[m * 4 + h] = pes;
            ed[m * 4 + h] = ped;
          }
        }
      }
    }
  }
}

// ---------------- attention logits (layer 3 only: H=1, C=128) ----------------

template <int H, int C>
__global__ __launch_bounds__(256) void k_att(const unsigned short* __restrict__ hbuf,
                                             const float* __restrict__ a_s, const float* __restrict__ a_d,
                                             float* __restrict__ es, float* __restrict__ ed) {
  int idx = blockIdx.x * 256 + threadIdx.x;
  if (idx >= N_NODES * H) return;
  int n = idx / H;
  int h = idx % H;
  const unsigned short* row = hbuf + (size_t)n * (H * C) + h * C;
  const float* asp = a_s + h * C;
  const float* adp = a_d + h * C;
  float s = 0.f, d = 0.f;
#pragma unroll
  for (int c = 0; c < C; c += 8) {
    uint4 u = *(const uint4*)(row + c);
    float4 s0 = *(const float4*)(asp + c);
    float4 s1 = *(const float4*)(asp + c + 4);
    float4 d0 = *(const float4*)(adp + c);
    float4 d1 = *(const float4*)(adp + c + 4);
    float v0 = b2f((unsigned short)(u.x & 0xffff)), v1 = b2f((unsigned short)(u.x >> 16));
    float v2 = b2f((unsigned short)(u.y & 0xffff)), v3 = b2f((unsigned short)(u.y >> 16));
    float v4 = b2f((unsigned short)(u.z & 0xffff)), v5 = b2f((unsigned short)(u.z >> 16));
    float v6 = b2f((unsigned short)(u.w & 0xffff)), v7 = b2f((unsigned short)(u.w >> 16));
    s += v0 * s0.x + v1 * s0.y + v2 * s0.z + v3 * s0.w + v4 * s1.x + v5 * s1.y + v6 * s1.z + v7 * s1.w;
    d += v0 * d0.x + v1 * d0.y + v2 * d0.z + v3 * d0.w + v4 * d1.x + v5 * d1.y + v6 * d1.z + v7 * d1.w;
  }
  es[idx] = s;
  ed[idx] = d;
}

// ---------------- edge logits (CSR-ordered, edge-parallel) ----------------

template <int H>
__global__ __launch_bounds__(256) void k_edge_logits(const float* __restrict__ es, const float* __restrict__ ed,
                                                     const int* __restrict__ csr, const int* __restrict__ csr_dst,
                                                     float* __restrict__ ew) {
  int p = blockIdx.x * 256 + threadIdx.x;
  if (p >= E_TOT) return;
  int s = csr[p], d = csr_dst[p];
  if (H == 4) {
    float4 a = *(const float4*)(es + (size_t)s * 4);
    float4 b = *(const float4*)(ed + (size_t)d * 4);
    float4 e;
    e.x = a.x + b.x; e.x = e.x > 0.f ? e.x : 0.2f * e.x;
    e.y = a.y + b.y; e.y = e.y > 0.f ? e.y : 0.2f * e.y;
    e.z = a.z + b.z; e.z = e.z > 0.f ? e.z : 0.2f * e.z;
    e.w = a.w + b.w; e.w = e.w > 0.f ? e.w : 0.2f * e.w;
    *(float4*)(ew + (size_t)p * 4) = e;
  } else {
    float e = es[s] + ed[d];
    ew[p] = e > 0.f ? e : 0.2f * e;
  }
}

// ---------------- softmax normalize (in place): ew -> alpha ----------------
// Per (node,head): m = max, denom = sum exp, then ew := exp(ew-m)/denom.

template <int H>
__global__ __launch_bounds__(256) void k_stats(float* __restrict__ ew, const int* __restrict__ offs,
                                               const int* __restrict__ deg) {
  int idx = blockIdx.x * 256 + threadIdx.x;
  if (idx >= N_NODES * H) return;
  int n = (H == 1) ? idx : (idx >> 2);
  int h = (H == 1) ? 0 : (idx & 3);
  float* p = ew + (size_t)offs[n] * H + h;
  int c = deg[n];
  float m = -1e30f;
  for (int i = 0; i < c; i++) m = fmaxf(m, p[(size_t)i * H]);
  float s = 0.f;
  for (int i = 0; i < c; i++) s += __expf(p[(size_t)i * H] - m);
  float inv = 1.0f / fmaxf(s, 1e-16f);
  for (int i = 0; i < c; i++) p[(size_t)i * H] = __expf(p[(size_t)i * H] - m) * inv;
}

// ---------------- aggregation (lean: alpha load + gather + FMA) ----------------

__device__ __forceinline__ void acc4(float* acc, float w, uint2 u) {
  acc[0] += w * b2f((unsigned short)(u.x & 0xffff));
  acc[1] += w * b2f((unsigned short)(u.x >> 16));
  acc[2] += w * b2f((unsigned short)(u.y & 0xffff));
  acc[3] += w * b2f((unsigned short)(u.y >> 16));
}
__device__ __forceinline__ void acc2(float* acc, float w, unsigned int u) {
  acc[0] += w * b2f((unsigned short)(u & 0xffff));
  acc[1] += w * b2f((unsigned short)(u >> 16));
}

template <int H, int C>
__global__ __launch_bounds__(256) void k_aggregate(const unsigned short* __restrict__ hbuf,
                                                   const float* __restrict__ ew,
                                                   const int* __restrict__ offs, const int* __restrict__ deg,
                                                   const int* __restrict__ csr, const float* __restrict__ bias,
                                                   unsigned short* __restrict__ out, int applyElu) {
  constexpr int F = H * C;
  constexpr int VPL = F / 64;  // 4 (H=4,C=64) or 2 (H=1,C=128)
  int wave = threadIdx.x >> 6;
  int lane = threadIdx.x & 63;
  int n = blockIdx.x * 4 + wave;
  if (n >= N_NODES) return;
  int head = (H == 1) ? 0 : (lane >> 4);
  int start = offs[n];
  int cnt = deg[n];
  const float* ewp = ew + (size_t)start * H + head;
  const int* csrp = csr + start;

  float acc[VPL];
#pragma unroll
  for (int j = 0; j < VPL; j++) acc[j] = 0.f;

  int i = 0;
  for (; i + 4 <= cnt; i += 4) {
    int s0 = csrp[i], s1 = csrp[i + 1], s2 = csrp[i + 2], s3 = csrp[i + 3];
    float w0 = ewp[(size_t)(i + 0) * H];
    float w1 = ewp[(size_t)(i + 1) * H];
    float w2 = ewp[(size_t)(i + 2) * H];
    float w3 = ewp[(size_t)(i + 3) * H];
    if (VPL == 4) {
      uint2 u0 = *(const uint2*)(hbuf + (size_t)s0 * F + lane * 4);
      uint2 u1 = *(const uint2*)(hbuf + (size_t)s1 * F + lane * 4);
      uint2 u2 = *(const uint2*)(hbuf + (size_t)s2 * F + lane * 4);
      uint2 u3 = *(const uint2*)(hbuf + (size_t)s3 * F + lane * 4);
      acc4(acc, w0, u0); acc4(acc, w1, u1); acc4(acc, w2, u2); acc4(acc, w3, u3);
    } else {
      unsigned int u0 = *(const unsigned int*)(hbuf + (size_t)s0 * F + lane * 2);
      unsigned int u1 = *(const unsigned int*)(hbuf + (size_t)s1 * F + lane * 2);
      unsigned int u2 = *(const unsigned int*)(hbuf + (size_t)s2 * F + lane * 2);
      unsigned int u3 = *(const unsigned int*)(hbuf + (size_t)s3 * F + lane * 2);
      acc2(acc, w0, u0); acc2(acc, w1, u1); acc2(acc, w2, u2); acc2(acc, w3, u3);
    }
  }
  for (; i < cnt; i++) {
    int s = csrp[i];
    float w = ewp[(size_t)i * H];
    if (VPL == 4) {
      uint2 u = *(const uint2*)(hbuf + (size_t)s * F + lane * 4);
      acc4(acc, w, u);
    } else {
      unsigned int u = *(const unsigned int*)(hbuf + (size_t)s * F + lane * 2);
      acc2(acc, w, u);
    }
  }

  unsigned short ob[VPL];
#pragma unroll
  for (int j = 0; j < VPL; j++) {
    float v = acc[j] + bias[lane * VPL + j];
    if (applyElu) v = v > 0.f ? v : expm1f(v);
    ob[j] = f2b(v);
  }
  if (VPL == 4) {
    ushort4 o = make_ushort4(ob[0], ob[1], ob[2], ob[3]);
    *(ushort4*)(out + (size_t)n * F + lane * 4) = o;
  } else {
    ushort2 o = make_ushort2(ob[0], ob[1]);
    *(ushort2*)(out + (size_t)n * F + lane * 2) = o;
  }
}

// ---------------- per-graph mean pool (segmented, batch sorted) ----------------

__global__ __launch_bounds__(256) void k_pool_seg(const unsigned short* __restrict__ feat,
                                                  const int* __restrict__ gptr, const int* __restrict__ gcnt,
                                                  float* __restrict__ pool) {
  int wave = threadIdx.x >> 6;
  int lane = threadIdx.x & 63;
  int g = blockIdx.x * 4 + wave;
  if (g >= N_GRAPHS_C) return;
  int start = gptr[g];
  int c = gcnt[g];
  float a0 = 0.f, a1 = 0.f;
  int i = 0;
  for (; i + 2 <= c; i += 2) {
    unsigned int u0 = *(const unsigned int*)(feat + (size_t)(start + i) * 128 + lane * 2);
    unsigned int u1 = *(const unsigned int*)(feat + (size_t)(start + i + 1) * 128 + lane * 2);
    a0 += b2f((unsigned short)(u0 & 0xffff)) + b2f((unsigned short)(u1 & 0xffff));
    a1 += b2f((unsigned short)(u0 >> 16)) + b2f((unsigned short)(u1 >> 16));
  }
  if (i < c) {
    unsigned int u = *(const unsigned int*)(feat + (size_t)(start + i) * 128 + lane * 2);
    a0 += b2f((unsigned short)(u & 0xffff));
    a1 += b2f((unsigned short)(u >> 16));
  }
  float invc = 1.0f / fmaxf((float)c, 1.0f);
  pool[(size_t)g * 128 + lane * 2 + 0] = a0 * invc;
  pool[(size_t)g * 128 + lane * 2 + 1] = a1 * invc;
}

// ---------------- MLP readout: 128 -> 64 -> 32 -> 4 ----------------

__global__ __launch_bounds__(128) void k_readout(const float* __restrict__ pool,
                                                 const float* __restrict__ mW0, const float* __restrict__ mb0,
                                                 const float* __restrict__ mW1, const float* __restrict__ mb1,
                                                 const float* __restrict__ mW2, const float* __restrict__ mb2,
                                                 float* __restrict__ out) {
  __shared__ float p[128];
  __shared__ float y1[64];
  __shared__ float y2[32];
  int g = blockIdx.x;
  int t = threadIdx.x;
  p[t] = pool[(size_t)g * 128 + t];
  __syncthreads();
  if (t < 64) {
    float a = mb0[t];
#pragma unroll 4
    for (int k = 0; k < 128; k++) a += p[k] * mW0[k * 64 + t];
    y1[t] = a > 0.f ? a : 0.f;
  }
  __syncthreads();
  if (t < 32) {
    float a = mb1[t];
#pragma unroll 4
    for (int k = 0; k < 64; k++) a += y1[k] * mW1[k * 32 + t];
    y2[t] = a > 0.f ? a : 0.f;
  }
  __syncthreads();
  if (t < 4) {
    float a = mb2[t];
#pragma unroll 4
    for (int k = 0; k < 32; k++) a += y2[k] * mW2[k * 4 + t];
    out[(size_t)g * 4 + t] = a;
  }
}

// ---------------- host side ----------------

extern "C" void kernel_launch(void* const* d_in, const int* in_sizes, int n_in,
                              void* d_out, int out_size, void* d_ws, size_t ws_size,
                              hipStream_t stream) {
  const float* x = (const float*)d_in[0];
  const int* ei = (const int*)d_in[1];
  const int* batch = (const int*)d_in[2];
  const float* W0 = (const float*)d_in[4];
  const float* as0 = (const float*)d_in[5];
  const float* ad0 = (const float*)d_in[6];
  const float* b0 = (const float*)d_in[7];
  const float* W1 = (const float*)d_in[8];
  const float* as1 = (const float*)d_in[9];
  const float* ad1 = (const float*)d_in[10];
  const float* b1 = (const float*)d_in[11];
  const float* W2 = (const float*)d_in[12];
  const float* as2 = (const float*)d_in[13];
  const float* ad2 = (const float*)d_in[14];
  const float* b2 = (const float*)d_in[15];
  const float* W3 = (const float*)d_in[16];
  const float* as3 = (const float*)d_in[17];
  const float* ad3 = (const float*)d_in[18];
  const float* b3 = (const float*)d_in[19];
  const float* mW0 = (const float*)d_in[20];
  const float* mb0 = (const float*)d_in[21];
  const float* mW1 = (const float*)d_in[22];
  const float* mb1 = (const float*)d_in[23];
  const float* mW2 = (const float*)d_in[24];
  const float* mb2 = (const float*)d_in[25];
  float* out = (float*)d_out;

  char* ws = (char*)d_ws;
  size_t cur = 0;
  auto alloc = [&](size_t bytes) -> char* {
    char* p = ws + cur;
    cur += (bytes + 255) & ~(size_t)255;
    return p;
  };
  unsigned short* featA = (unsigned short*)alloc((size_t)N_NODES * 256 * 2);
  unsigned short* hB = (unsigned short*)alloc((size_t)N_NODES * 256 * 2);
  unsigned short* xb = (unsigned short*)alloc((size_t)N_NODES * 64 * 2);
  unsigned short* wt0 = (unsigned short*)alloc((size_t)256 * 64 * 2);
  unsigned short* wt1 = (unsigned short*)alloc((size_t)256 * 256 * 2);
  unsigned short* wt2 = (unsigned short*)alloc((size_t)256 * 256 * 2);
  unsigned short* wt3 = (unsigned short*)alloc((size_t)128 * 256 * 2);
  float* es = (float*)alloc((size_t)N_NODES * 4 * sizeof(float));
  float* ed = (float*)alloc((size_t)N_NODES * 4 * sizeof(float));
  float* ew = (float*)alloc((size_t)E_TOT * 4 * sizeof(float));
  int* deg = (int*)alloc((size_t)N_NODES * sizeof(int));
  int* offs = (int*)alloc((size_t)N_NODES * sizeof(int));
  int* cursor = (int*)alloc((size_t)N_NODES * sizeof(int));
  int* csr = (int*)alloc((size_t)E_TOT * sizeof(int));
  int* csr_dst = (int*)alloc((size_t)E_TOT * sizeof(int));
  float* pool = (float*)alloc((size_t)N_GRAPHS_C * 128 * sizeof(float));
  int* gcnt = (int*)alloc((size_t)N_GRAPHS_C * sizeof(int));
  int* gptr = (int*)alloc((size_t)N_GRAPHS_C * sizeof(int));
  int* counter = (int*)alloc(256);
  (void)ws_size; (void)in_sizes; (void)n_in; (void)out_size;

  // ---- conversions ----
  k_cvt_x<<<ceil_div(N_NODES * 64 / 4, 256), 256, 0, stream>>>(x, xb, N_NODES * 64 / 4);
  k_cvt_wt<<<ceil_div(64 * 256, 256), 256, 0, stream>>>(W0, wt0, 64, 256);
  k_cvt_wt<<<ceil_div(256 * 256, 256), 256, 0, stream>>>(W1, wt1, 256, 256);
  k_cvt_wt<<<ceil_div(256 * 256, 256), 256, 0, stream>>>(W2, wt2, 256, 256);
  k_cvt_wt<<<ceil_div(256 * 128, 256), 256, 0, stream>>>(W3, wt3, 256, 128);

  // ---- CSR build + graph segments ----
  hipMemsetAsync(deg, 0, (size_t)N_NODES * sizeof(int), stream);
  hipMemsetAsync(counter, 0, sizeof(int), stream);
  hipMemsetAsync(gcnt, 0, (size_t)N_GRAPHS_C * sizeof(int), stream);
  k_count_deg<<<ceil_div(N_EDGES, 256), 256, 0, stream>>>(ei, deg);
  k_scan<<<ceil_div(N_NODES, 256), 256, 0, stream>>>(deg, offs, cursor, counter);
  k_scatter<<<ceil_div(E_TOT, 256), 256, 0, stream>>>(ei, cursor, csr, csr_dst);
  k_gcount<<<ceil_div(N_NODES, 256), 256, 0, stream>>>(batch, gcnt);
  k_gscan<<<1, 256, 0, stream>>>(gcnt, gptr);

  int gm = ceil_div(N_NODES, 128);
  dim3 g256(gm, 2), g128(gm, 1);
  int aggBlocks = ceil_div(N_NODES, 4);
  int edgeBlocks = ceil_div(E_TOT, 256);
  int statBlocks4 = ceil_div(N_NODES * 4, 256);
  int statBlocks1 = ceil_div(N_NODES, 256);

  // ---- layer 0: 64 -> 4x64 ----
  k_gemm_bf16<1><<<g256, 256, 0, stream>>>(xb, wt0, hB, N_NODES, 64, 256, as0, ad0, es, ed);
  k_edge_logits<4><<<edgeBlocks, 256, 0, stream>>>(es, ed, csr, csr_dst, ew);
  k_stats<4><<<statBlocks4, 256, 0, stream>>>(ew, offs, deg);
  k_aggregate<4, 64><<<aggBlocks, 256, 0, stream>>>(hB, ew, offs, deg, csr, b0, featA, 1);

  // ---- layer 1 ----
  k_gemm_bf16<1><<<g256, 256, 0, stream>>>(featA, wt1, hB, N_NODES, 256, 256, as1, ad1, es, ed);
  k_edge_logits<4><<<edgeBlocks, 256, 0, stream>>>(es, ed, csr, csr_dst, ew);
  k_stats<4><<<statBlocks4, 256, 0, stream>>>(ew, offs, deg);
  k_aggregate<4, 64><<<aggBlocks, 256, 0, stream>>>(hB, ew, offs, deg, csr, b1, featA, 1);

  // ---- layer 2 ----
  k_gemm_bf16<1><<<g256, 256, 0, stream>>>(featA, wt2, hB, N_NODES, 256, 256, as2, ad2, es, ed);
  k_edge_logits<4><<<edgeBlocks, 256, 0, stream>>>(es, ed, csr, csr_dst, ew);
  k_stats<4><<<statBlocks4, 256, 0, stream>>>(ew, offs, deg);
  k_aggregate<4, 64><<<aggBlocks, 256, 0, stream>>>(hB, ew, offs, deg, csr, b2, featA, 1);

  // ---- layer 3: 256 -> 128, 1 head, no ELU ----
  k_gemm_bf16<0><<<g128, 256, 0, stream>>>(featA, wt3, hB, N_NODES, 256, 128, nullptr, nullptr, nullptr, nullptr);
  k_att<1, 128><<<statBlocks1, 256, 0, stream>>>(hB, as3, ad3, es, ed);
  k_edge_logits<1><<<edgeBlocks, 256, 0, stream>>>(es, ed, csr, csr_dst, ew);
  k_stats<1><<<statBlocks1, 256, 0, stream>>>(ew, offs, deg);
  k_aggregate<1, 128><<<aggBlocks, 256, 0, stream>>>(hB, ew, offs, deg, csr, b3, featA, 0);

  // ---- pool + readout ----
  k_pool_seg<<<ceil_div(N_GRAPHS_C, 4), 256, 0, stream>>>(featA, gptr, gcnt, pool);
  k_readout<<<N_GRAPHS_C, 128, 0, stream>>>(pool, mW0, mb0, mW1, mb1, mW2, mb2, out);
}